// Round 2
// baseline (3220.698 us; speedup 1.0000x reference)
//
#include <hip/hip_runtime.h>
#include <math.h>

// VNLayer: N=20000 nodes, E=240000 edges, H=256, SD=128, C=4, FEAT=480
// fp32, fused-edge implementation (round 2): minimal workspace (~32MB).
//  k_nfs  : nfs = node_feat[:, :128] @ w_scalar * 1/sqrt(128)          [N,128]
//  k_edge : per 32-edge block: geometry (ip,dn) -> cm MLP (K=400) -> msg
//           -> vr/rv MLPs -> geometric update; atomic scatters to
//           agg_feat / agg_vr / agg_rv / cnt.  No msg/ip/dn global bufs.
//  k_node : mean by cnt; vf MLP; ft->f2t chain -> ds; write all outputs.

#define FEAT 480
#define HDIM 256
#define SDIM 128

__device__ __forceinline__ float silu_f(float x) {
    return x / (1.0f + __expf(-x));
}

// ---------------------------------------------------------------- k_nfs
__global__ __launch_bounds__(256) void k_nfs(
    const float* __restrict__ node_feat, const float* __restrict__ w_scalar,
    float* __restrict__ nfs)
{
    __shared__ float At[32][20];
    __shared__ float Wt[16][128];
    const int t  = threadIdx.x;
    const int m0 = blockIdx.x * 32;
    const int c4 = (t & 31) * 4;
    const int rg = t >> 5;                    // 0..7, rows rg*4+j
    float acc[4][4] = {};
    for (int k0 = 0; k0 < 128; k0 += 16) {
        if (t < 128) {
            const int r = t >> 2, kk = (t & 3) * 4;
            *(float4*)&At[r][kk] =
                *(const float4*)&node_feat[(size_t)(m0 + r) * FEAT + k0 + kk];
        }
        #pragma unroll
        for (int i = 0; i < 2; ++i) {
            const int p  = t + i * 256;       // 512 float4 total
            const int wr = p >> 5, wc = (p & 31) * 4;
            *(float4*)&Wt[wr][wc] =
                *(const float4*)&w_scalar[(size_t)(k0 + wr) * SDIM + wc];
        }
        __syncthreads();
        #pragma unroll
        for (int kk = 0; kk < 16; ++kk) {
            const float4 w = *(const float4*)&Wt[kk][c4];
            #pragma unroll
            for (int j = 0; j < 4; ++j) {
                const float a = At[rg * 4 + j][kk];
                acc[j][0] = fmaf(a, w.x, acc[j][0]);
                acc[j][1] = fmaf(a, w.y, acc[j][1]);
                acc[j][2] = fmaf(a, w.z, acc[j][2]);
                acc[j][3] = fmaf(a, w.w, acc[j][3]);
            }
        }
        __syncthreads();
    }
    const float s = 0.08838834764831845f;     // 1/sqrt(128)
    #pragma unroll
    for (int j = 0; j < 4; ++j) {
        float4 o;
        o.x = acc[j][0] * s; o.y = acc[j][1] * s;
        o.z = acc[j][2] * s; o.w = acc[j][3] * s;
        *(float4*)&nfs[(size_t)(m0 + rg * 4 + j) * SDIM + c4] = o;
    }
}

// ---------------------------------------------------------------- k_edge
// 32 edges per block, 256 threads. LDS total = 62,720 B (< 64 KB).
__global__ __launch_bounds__(256) void k_edge(
    const float* __restrict__ nfs, const float* __restrict__ vn_feat,
    const float* __restrict__ node_pos, const float* __restrict__ vn_pos,
    const int* __restrict__ eidx,
    const float* __restrict__ w1, const float* __restrict__ b1,
    const float* __restrict__ w2, const float* __restrict__ b2,
    const float* __restrict__ vrw1, const float* __restrict__ vrb1,
    const float* __restrict__ vrw2, const float* __restrict__ vrb2,
    const float* __restrict__ rvw1, const float* __restrict__ rvb1,
    const float* __restrict__ rvw2, const float* __restrict__ rvb2,
    float* __restrict__ agg_feat, float* __restrict__ agg_vr,
    float* __restrict__ agg_rv, float* __restrict__ cnt, int E)
{
    __shared__ float At[32][8];       // 1 KB   cm A staging; later wvr[32][4]
    __shared__ float Wt[8][256];      // 8 KB   weight tiles
    __shared__ float HM[32][256];     // 32 KB  cm hidden, then msg
    __shared__ float Hv[32][132];     // 16.9KB vr/rv hidden half (128 cols)
    __shared__ float ipS[32][16];     // 2 KB   gram; later wrv[32][16]
    __shared__ float dnS[32][12];     // 1.5 KB
    __shared__ int rowi[32], coli[32];

    const int t  = threadIdx.x;
    const int e0 = blockIdx.x * 32;

    // ---- geometry (t<32: one edge per thread) ----
    if (t < 32) {
        const int r = eidx[e0 + t];
        const int c = eidx[E + e0 + t];
        rowi[t] = r; coli[t] = c;
        const float px = node_pos[r * 3 + 0];
        const float py = node_pos[r * 3 + 1];
        const float pz = node_pos[r * 3 + 2];
        float d[4][3];
        #pragma unroll
        for (int ch = 0; ch < 4; ++ch) {
            d[ch][0] = px - vn_pos[(size_t)c * 12 + ch * 3 + 0];
            d[ch][1] = py - vn_pos[(size_t)c * 12 + ch * 3 + 1];
            d[ch][2] = pz - vn_pos[(size_t)c * 12 + ch * 3 + 2];
        }
        float ss = 0.f;
        float ipv[16];
        #pragma unroll
        for (int ci = 0; ci < 4; ++ci) {
            #pragma unroll
            for (int ck = 0; ck < 4; ++ck) {
                const float v = d[ci][0]*d[ck][0] + d[ci][1]*d[ck][1] + d[ci][2]*d[ck][2];
                ipv[ci * 4 + ck] = v;
                ss += v * v;
            }
        }
        const float inrm = 1.0f / fmaxf(sqrtf(ss), 1e-8f);
        #pragma unroll
        for (int i = 0; i < 16; ++i) ipS[t][i] = ipv[i] * inrm;
        #pragma unroll
        for (int ch = 0; ch < 4; ++ch) {
            const float nn = sqrtf(d[ch][0]*d[ch][0] + d[ch][1]*d[ch][1] + d[ch][2]*d[ch][2]);
            const float s = 1.0f / fmaxf(nn, 1e-8f);
            dnS[t][ch * 3 + 0] = d[ch][0] * s;
            dnS[t][ch * 3 + 1] = d[ch][1] * s;
            dnS[t][ch * 3 + 2] = d[ch][2] * s;
        }
        atomicAdd(&cnt[r], 1.0f);
    }
    __syncthreads();

    const int c4 = (t & 63) * 4;      // N=256 mapping
    const int rg = t >> 6;            // rows rg*8+j

    // ===== cm layer 1 (K=400) =====
    float acc[8][4] = {};
    for (int k0 = 0; k0 < 400; k0 += 8) {
        if (t < 64) {                 // gather-concat A tile 32x8
            const int r = t >> 1, kk = (t & 1) * 4;
            float4 v;
            if (k0 < 128)      v = *(const float4*)&nfs[(size_t)rowi[r] * SDIM + k0 + kk];
            else if (k0 < 384) v = *(const float4*)&vn_feat[(size_t)coli[r] * HDIM + (k0 - 128) + kk];
            else               v = *(float4*)&ipS[r][(k0 - 384) + kk];
            *(float4*)&At[r][kk] = v;
        }
        #pragma unroll
        for (int i = 0; i < 2; ++i) {
            const int p  = t + i * 256;
            const int wr = p >> 6, wc = (p & 63) * 4;
            *(float4*)&Wt[wr][wc] = *(const float4*)&w1[(size_t)(k0 + wr) * HDIM + wc];
        }
        __syncthreads();
        #pragma unroll
        for (int kk = 0; kk < 8; ++kk) {
            const float4 w = *(const float4*)&Wt[kk][c4];
            #pragma unroll
            for (int j = 0; j < 8; ++j) {
                const float a = At[rg * 8 + j][kk];
                acc[j][0] = fmaf(a, w.x, acc[j][0]);
                acc[j][1] = fmaf(a, w.y, acc[j][1]);
                acc[j][2] = fmaf(a, w.z, acc[j][2]);
                acc[j][3] = fmaf(a, w.w, acc[j][3]);
            }
        }
        __syncthreads();
    }
    {
        const float4 bb = *(const float4*)&b1[c4];
        #pragma unroll
        for (int j = 0; j < 8; ++j) {
            float4 h;
            h.x = silu_f(acc[j][0] + bb.x); h.y = silu_f(acc[j][1] + bb.y);
            h.z = silu_f(acc[j][2] + bb.z); h.w = silu_f(acc[j][3] + bb.w);
            *(float4*)&HM[rg * 8 + j][c4] = h;
        }
    }
    __syncthreads();

    // ===== cm layer 2 (256 -> 256) =====
    float acc2[8][4] = {};
    for (int k0 = 0; k0 < 256; k0 += 8) {
        #pragma unroll
        for (int i = 0; i < 2; ++i) {
            const int p  = t + i * 256;
            const int wr = p >> 6, wc = (p & 63) * 4;
            *(float4*)&Wt[wr][wc] = *(const float4*)&w2[(size_t)(k0 + wr) * HDIM + wc];
        }
        __syncthreads();
        #pragma unroll
        for (int kk = 0; kk < 8; ++kk) {
            const float4 w = *(const float4*)&Wt[kk][c4];
            #pragma unroll
            for (int j = 0; j < 8; ++j) {
                const float a = HM[rg * 8 + j][k0 + kk];
                acc2[j][0] = fmaf(a, w.x, acc2[j][0]);
                acc2[j][1] = fmaf(a, w.y, acc2[j][1]);
                acc2[j][2] = fmaf(a, w.z, acc2[j][2]);
                acc2[j][3] = fmaf(a, w.w, acc2[j][3]);
            }
        }
        __syncthreads();
    }
    // msg = acc2 + b2 -> overwrite HM; scatter to agg_feat
    {
        const float4 b2v = *(const float4*)&b2[c4];
        #pragma unroll
        for (int j = 0; j < 8; ++j) {
            const int r = rg * 8 + j;
            float4 m;
            m.x = acc2[j][0] + b2v.x; m.y = acc2[j][1] + b2v.y;
            m.z = acc2[j][2] + b2v.z; m.w = acc2[j][3] + b2v.w;
            *(float4*)&HM[r][c4] = m;
            float* ag = &agg_feat[(size_t)rowi[r] * HDIM + c4];
            atomicAdd(ag + 0, m.x); atomicAdd(ag + 1, m.y);
            atomicAdd(ag + 2, m.z); atomicAdd(ag + 3, m.w);
        }
    }
    __syncthreads();

    // ===== vr / rv MLPs on msg (in HM), split-hidden halves =====
    const int c4b = (t & 31) * 4;     // N=128 mapping
    const int rgb = t >> 5;           // rows rgb*4+j
    float svr  = (t < 128) ? vrb2[t & 3] : 0.f;    // wvr[r=t>>2][c=t&3]
    float srv0 = rvb2[t & 15];                     // wrv[r=t>>4][c=t&15]
    float srv1 = srv0;                             // wrv[16+(t>>4)][c]

    // ---- vr ----
    #pragma unroll
    for (int half = 0; half < 2; ++half) {
        const int hc0 = half * 128;
        float a1[4][4] = {};
        for (int k0 = 0; k0 < 256; k0 += 8) {
            const int wr = t >> 5, wc = (t & 31) * 4;
            *(float4*)&Wt[wr][wc] = *(const float4*)&vrw1[(size_t)(k0 + wr) * HDIM + hc0 + wc];
            __syncthreads();
            #pragma unroll
            for (int kk = 0; kk < 8; ++kk) {
                const float4 w = *(const float4*)&Wt[kk][c4b];
                #pragma unroll
                for (int j = 0; j < 4; ++j) {
                    const float a = HM[rgb * 4 + j][k0 + kk];
                    a1[j][0] = fmaf(a, w.x, a1[j][0]); a1[j][1] = fmaf(a, w.y, a1[j][1]);
                    a1[j][2] = fmaf(a, w.z, a1[j][2]); a1[j][3] = fmaf(a, w.w, a1[j][3]);
                }
            }
            __syncthreads();
        }
        {
            const float4 bb = *(const float4*)&vrb1[hc0 + c4b];
            #pragma unroll
            for (int j = 0; j < 4; ++j) {
                float4 h;
                h.x = silu_f(a1[j][0] + bb.x); h.y = silu_f(a1[j][1] + bb.y);
                h.z = silu_f(a1[j][2] + bb.z); h.w = silu_f(a1[j][3] + bb.w);
                *(float4*)&Hv[rgb * 4 + j][c4b] = h;
            }
        }
        __syncthreads();
        if (t < 128) {                // layer-2 partial, N=4
            const int r = t >> 2, c = t & 3;
            float s = 0.f;
            for (int k = 0; k < 128; ++k)
                s = fmaf(Hv[r][k], vrw2[(size_t)(hc0 + k) * 4 + c], s);
            svr += s;
        }
        __syncthreads();
    }
    if (t < 128) ((float(*)[4])At)[t >> 2][t & 3] = svr;   // wvr overlays At

    // ---- rv ----
    #pragma unroll
    for (int half = 0; half < 2; ++half) {
        const int hc0 = half * 128;
        float a1[4][4] = {};
        for (int k0 = 0; k0 < 256; k0 += 8) {
            const int wr = t >> 5, wc = (t & 31) * 4;
            *(float4*)&Wt[wr][wc] = *(const float4*)&rvw1[(size_t)(k0 + wr) * HDIM + hc0 + wc];
            __syncthreads();
            #pragma unroll
            for (int kk = 0; kk < 8; ++kk) {
                const float4 w = *(const float4*)&Wt[kk][c4b];
                #pragma unroll
                for (int j = 0; j < 4; ++j) {
                    const float a = HM[rgb * 4 + j][k0 + kk];
                    a1[j][0] = fmaf(a, w.x, a1[j][0]); a1[j][1] = fmaf(a, w.y, a1[j][1]);
                    a1[j][2] = fmaf(a, w.z, a1[j][2]); a1[j][3] = fmaf(a, w.w, a1[j][3]);
                }
            }
            __syncthreads();
        }
        {
            const float4 bb = *(const float4*)&rvb1[hc0 + c4b];
            #pragma unroll
            for (int j = 0; j < 4; ++j) {
                float4 h;
                h.x = silu_f(a1[j][0] + bb.x); h.y = silu_f(a1[j][1] + bb.y);
                h.z = silu_f(a1[j][2] + bb.z); h.w = silu_f(a1[j][3] + bb.w);
                *(float4*)&Hv[rgb * 4 + j][c4b] = h;
            }
        }
        __syncthreads();
        {                             // layer-2 partial, N=16, rows r and r+16
            const int r = t >> 4, c = t & 15;
            float s0 = 0.f, s1 = 0.f;
            for (int k = 0; k < 128; ++k) {
                const float w0 = rvw2[(size_t)(hc0 + k) * 16 + c];
                s0 = fmaf(Hv[r][k],      w0, s0);
                s1 = fmaf(Hv[16 + r][k], w0, s1);
            }
            srv0 += s0; srv1 += s1;
        }
        __syncthreads();
    }
    ((float(*)[16])ipS)[t >> 4][t & 15]        = srv0;     // wrv overlays ipS
    ((float(*)[16])ipS)[16 + (t >> 4)][t & 15] = srv1;
    __syncthreads();

    // ===== geometric update + scatter (t<32) =====
    if (t < 32) {
        const int rr = rowi[t];
        float dn[12];
        #pragma unroll
        for (int i = 0; i < 12; ++i) dn[i] = dnS[t][i];
        const float* wv  = ((float(*)[4])At)[t];
        const float* wrw = ((float(*)[16])ipS)[t];
        #pragma unroll
        for (int j = 0; j < 3; ++j) {
            float v = 0.f;
            #pragma unroll
            for (int c = 0; c < 4; ++c) v = fmaf(wv[c], dn[c * 3 + j], v);
            atomicAdd(&agg_vr[(size_t)rr * 3 + j], 0.5f * v);     // inv = 1/sqrt(4)
        }
        #pragma unroll
        for (int u = 0; u < 4; ++u) {
            #pragma unroll
            for (int j = 0; j < 3; ++j) {
                float v = 0.f;
                #pragma unroll
                for (int c = 0; c < 4; ++c) v = fmaf(wrw[c * 4 + u], dn[c * 3 + j], v);
                atomicAdd(&agg_rv[(size_t)rr * 12 + u * 3 + j], -0.5f * v);
            }
        }
    }
}

// ---------------------------------------------------------------- k_node helpers
__device__ __forceinline__ void gemm16x256(
    const float Ab[16][260], float Wt[16][256], const float* __restrict__ Wsrc,
    float acc[4][4], const int t, const int c4, const int rg)
{
    #pragma unroll
    for (int j = 0; j < 4; ++j) { acc[j][0]=0.f; acc[j][1]=0.f; acc[j][2]=0.f; acc[j][3]=0.f; }
    for (int k0 = 0; k0 < 256; k0 += 16) {
        #pragma unroll
        for (int i = 0; i < 4; ++i) {
            const int p  = t + i * 256;
            const int wr = p >> 6, wc = (p & 63) * 4;
            *(float4*)&Wt[wr][wc] = *(const float4*)&Wsrc[(size_t)(k0 + wr) * 256 + wc];
        }
        __syncthreads();
        #pragma unroll
        for (int kk = 0; kk < 16; ++kk) {
            const float4 w = *(const float4*)&Wt[kk][c4];
            #pragma unroll
            for (int j = 0; j < 4; ++j) {
                const float a = Ab[rg * 4 + j][k0 + kk];
                acc[j][0] = fmaf(a, w.x, acc[j][0]); acc[j][1] = fmaf(a, w.y, acc[j][1]);
                acc[j][2] = fmaf(a, w.z, acc[j][2]); acc[j][3] = fmaf(a, w.w, acc[j][3]);
            }
        }
        __syncthreads();
    }
}

// ---------------------------------------------------------------- k_node
__global__ __launch_bounds__(256) void k_node(
    const float* __restrict__ node_feat, const float* __restrict__ node_pos,
    const float* __restrict__ vn_feat, const float* __restrict__ vn_pos,
    const float* __restrict__ agg_feat, const float* __restrict__ agg_vr,
    const float* __restrict__ agg_rv, const float* __restrict__ cnt,
    const float* __restrict__ ftw1, const float* __restrict__ ftb1,
    const float* __restrict__ ftw2, const float* __restrict__ ftb2,
    const float* __restrict__ f2tw1, const float* __restrict__ f2tb1,
    const float* __restrict__ f2tw2, const float* __restrict__ f2tb2,
    const float* __restrict__ vfw1, const float* __restrict__ vfb1,
    const float* __restrict__ vfw2, const float* __restrict__ vfb2,
    float* __restrict__ out, int Nn)
{
    __shared__ float At[16][260];
    __shared__ float Ht[16][260];
    __shared__ float Wt[16][256];
    __shared__ float rc[16];
    const int t  = threadIdx.x;
    const int n0 = blockIdx.x * 16;
    float* nf_out = out;
    float* np_out = out + (size_t)Nn * FEAT;
    float* vf_out = np_out + (size_t)Nn * 3;
    float* vp_out = vf_out + (size_t)Nn * HDIM;

    if (t < 16) rc[t] = 1.0f / fmaxf(cnt[n0 + t], 1.0f);
    __syncthreads();
    #pragma unroll
    for (int i = 0; i < 4; ++i) {             // At = agg_feat / cnt
        const int p = t + i * 256;
        const int r = p >> 6, cc = (p & 63) * 4;
        float4 v = *(const float4*)&agg_feat[(size_t)(n0 + r) * HDIM + cc];
        const float s = rc[r];
        v.x *= s; v.y *= s; v.z *= s; v.w *= s;
        *(float4*)&At[r][cc] = v;
    }
    __syncthreads();
    const int c4 = (t & 63) * 4;
    const int rg = t >> 6;                    // rows rg*4+j
    float acc[4][4];

    // ---- vf MLP ----
    gemm16x256(At, Wt, vfw1, acc, t, c4, rg);
    {
        const float4 bb = *(const float4*)&vfb1[c4];
        #pragma unroll
        for (int j = 0; j < 4; ++j) {
            float4 h;
            h.x = silu_f(acc[j][0] + bb.x); h.y = silu_f(acc[j][1] + bb.y);
            h.z = silu_f(acc[j][2] + bb.z); h.w = silu_f(acc[j][3] + bb.w);
            *(float4*)&Ht[rg * 4 + j][c4] = h;
        }
    }
    __syncthreads();
    gemm16x256(Ht, Wt, vfw2, acc, t, c4, rg);
    {
        const float4 bb = *(const float4*)&vfb2[c4];
        #pragma unroll
        for (int j = 0; j < 4; ++j) {
            const int r = rg * 4 + j;
            float4 v = *(const float4*)&vn_feat[(size_t)(n0 + r) * HDIM + c4];
            v.x += acc[j][0] + bb.x; v.y += acc[j][1] + bb.y;
            v.z += acc[j][2] + bb.z; v.w += acc[j][3] + bb.w;
            *(float4*)&vf_out[(size_t)(n0 + r) * HDIM + c4] = v;
        }
    }

    // ---- ft MLP ----
    gemm16x256(At, Wt, ftw1, acc, t, c4, rg);
    {
        const float4 bb = *(const float4*)&ftb1[c4];
        #pragma unroll
        for (int j = 0; j < 4; ++j) {
            float4 h;
            h.x = silu_f(acc[j][0] + bb.x); h.y = silu_f(acc[j][1] + bb.y);
            h.z = silu_f(acc[j][2] + bb.z); h.w = silu_f(acc[j][3] + bb.w);
            *(float4*)&Ht[rg * 4 + j][c4] = h;
        }
    }
    __syncthreads();
    gemm16x256(Ht, Wt, ftw2, acc, t, c4, rg);
    {
        const float4 bb = *(const float4*)&ftb2[c4];
        #pragma unroll
        for (int j = 0; j < 4; ++j) {          // x2 -> At (agg no longer needed)
            float4 v;
            v.x = acc[j][0] + bb.x; v.y = acc[j][1] + bb.y;
            v.z = acc[j][2] + bb.z; v.w = acc[j][3] + bb.w;
            *(float4*)&At[rg * 4 + j][c4] = v;
        }
    }
    __syncthreads();

    // ---- f2t MLP ----
    gemm16x256(At, Wt, f2tw1, acc, t, c4, rg);
    {
        const float4 bb = *(const float4*)&f2tb1[c4];
        #pragma unroll
        for (int j = 0; j < 4; ++j) {
            float4 h;
            h.x = silu_f(acc[j][0] + bb.x); h.y = silu_f(acc[j][1] + bb.y);
            h.z = silu_f(acc[j][2] + bb.z); h.w = silu_f(acc[j][3] + bb.w);
            *(float4*)&Ht[rg * 4 + j][c4] = h;
        }
    }
    __syncthreads();
    {   // layer 2, N=128: ds, fused residual into node_feat[:, :128]
        const int c4b = (t & 31) * 4;
        const int rgb = t >> 5;               // rows rgb*2+j, j<2
        float* Wfl = &Wt[0][0];
        float a3[2][4] = {};
        for (int k0 = 0; k0 < 256; k0 += 16) {
            #pragma unroll
            for (int i = 0; i < 2; ++i) {
                const int p  = t + i * 256;   // 512 float4 = 16x128
                const int wr = p >> 5, wc = (p & 31) * 4;
                *(float4*)&Wfl[wr * 128 + wc] =
                    *(const float4*)&f2tw2[(size_t)(k0 + wr) * SDIM + wc];
            }
            __syncthreads();
            #pragma unroll
            for (int kk = 0; kk < 16; ++kk) {
                const float4 w = *(const float4*)&Wfl[kk * 128 + c4b];
                #pragma unroll
                for (int j = 0; j < 2; ++j) {
                    const float a = Ht[rgb * 2 + j][k0 + kk];
                    a3[j][0] = fmaf(a, w.x, a3[j][0]); a3[j][1] = fmaf(a, w.y, a3[j][1]);
                    a3[j][2] = fmaf(a, w.z, a3[j][2]); a3[j][3] = fmaf(a, w.w, a3[j][3]);
                }
            }
            __syncthreads();
        }
        const float4 bb = *(const float4*)&f2tb2[c4b];
        #pragma unroll
        for (int j = 0; j < 2; ++j) {
            const int r = rgb * 2 + j;
            float4 v = *(const float4*)&node_feat[(size_t)(n0 + r) * FEAT + c4b];
            v.x += a3[j][0] + bb.x; v.y += a3[j][1] + bb.y;
            v.z += a3[j][2] + bb.z; v.w += a3[j][3] + bb.w;
            *(float4*)&nf_out[(size_t)(n0 + r) * FEAT + c4b] = v;
        }
    }

    // passthrough copy of node_feat cols 128..479
    for (int p = t; p < 16 * 352; p += 256) {
        const int r  = p / 352;
        const int cc = 128 + (p % 352);
        nf_out[(size_t)(n0 + r) * FEAT + cc] = node_feat[(size_t)(n0 + r) * FEAT + cc];
    }
    // position outputs
    if (t < 16) {
        const int n = n0 + t;
        const float s = rc[t];
        #pragma unroll
        for (int j = 0; j < 3; ++j)
            np_out[(size_t)n * 3 + j] = node_pos[(size_t)n * 3 + j] + agg_vr[(size_t)n * 3 + j] * s;
        #pragma unroll
        for (int j = 0; j < 12; ++j)
            vp_out[(size_t)n * 12 + j] = vn_pos[(size_t)n * 12 + j] + agg_rv[(size_t)n * 12 + j] * s;
    }
}

// ---------------------------------------------------------------- launch
extern "C" void kernel_launch(void* const* d_in, const int* in_sizes, int n_in,
                              void* d_out, int out_size, void* d_ws, size_t ws_size,
                              hipStream_t stream)
{
    (void)n_in; (void)out_size; (void)ws_size;
    const float* node_feat = (const float*)d_in[0];
    const float* node_pos  = (const float*)d_in[1];
    const float* vn_feat   = (const float*)d_in[2];
    const float* vn_pos    = (const float*)d_in[3];
    const int*   eidx      = (const int*)d_in[4];
    const float* w_scalar  = (const float*)d_in[5];
    const float* cm_w1  = (const float*)d_in[6];
    const float* cm_b1  = (const float*)d_in[7];
    const float* cm_w2  = (const float*)d_in[8];
    const float* cm_b2  = (const float*)d_in[9];
    const float* vr_w1  = (const float*)d_in[10];
    const float* vr_b1  = (const float*)d_in[11];
    const float* vr_w2  = (const float*)d_in[12];
    const float* vr_b2  = (const float*)d_in[13];
    const float* rv_w1  = (const float*)d_in[14];
    const float* rv_b1  = (const float*)d_in[15];
    const float* rv_w2  = (const float*)d_in[16];
    const float* rv_b2  = (const float*)d_in[17];
    const float* ft_w1  = (const float*)d_in[18];
    const float* ft_b1  = (const float*)d_in[19];
    const float* ft_w2  = (const float*)d_in[20];
    const float* ft_b2  = (const float*)d_in[21];
    const float* f2t_w1 = (const float*)d_in[22];
    const float* f2t_b1 = (const float*)d_in[23];
    const float* f2t_w2 = (const float*)d_in[24];
    const float* f2t_b2 = (const float*)d_in[25];
    const float* vf_w1  = (const float*)d_in[26];
    const float* vf_b1  = (const float*)d_in[27];
    const float* vf_w2  = (const float*)d_in[28];
    const float* vf_b2  = (const float*)d_in[29];

    const int Nn = in_sizes[0] / FEAT;        // 20000
    const int E  = in_sizes[4] / 2;           // 240000

    // workspace layout (floats): total Nn*(272+128) = 8.0M floats = 32 MB
    float* ws       = (float*)d_ws;
    float* agg_feat = ws;                                // Nn*256
    float* agg_vr   = agg_feat + (size_t)Nn * HDIM;      // Nn*3
    float* agg_rv   = agg_vr   + (size_t)Nn * 3;         // Nn*12
    float* cnt      = agg_rv   + (size_t)Nn * 12;        // Nn
    float* nfs      = cnt      + Nn;                     // Nn*128

    const size_t zero_bytes = (size_t)Nn * (HDIM + 3 + 12 + 1) * sizeof(float);
    hipMemsetAsync(agg_feat, 0, zero_bytes, stream);

    k_nfs<<<Nn / 32, 256, 0, stream>>>(node_feat, w_scalar, nfs);
    k_edge<<<E / 32, 256, 0, stream>>>(nfs, vn_feat, node_pos, vn_pos, eidx,
                                       cm_w1, cm_b1, cm_w2, cm_b2,
                                       vr_w1, vr_b1, vr_w2, vr_b2,
                                       rv_w1, rv_b1, rv_w2, rv_b2,
                                       agg_feat, agg_vr, agg_rv, cnt, E);
    k_node<<<Nn / 16, 256, 0, stream>>>(node_feat, node_pos, vn_feat, vn_pos,
                                        agg_feat, agg_vr, agg_rv, cnt,
                                        ft_w1, ft_b1, ft_w2, ft_b2,
                                        f2t_w1, f2t_b1, f2t_w2, f2t_b2,
                                        vf_w1, vf_b1, vf_w2, vf_b2,
                                        (float*)d_out, Nn);
}

// Round 3
// 1038.705 us; speedup vs baseline: 3.1007x; 3.1007x over previous
//
#include <hip/hip_runtime.h>
#include <hip/hip_bf16.h>
#include <math.h>

// VNLayer: N=20000 nodes, E=240000 edges, H=256, SD=128, C=4, FEAT=480
// Round 3: bf16 MFMA edge kernel (16x16x32, fp32 accum).
//  k_wprep: fp32 weights -> transposed padded bf16 (W[n][k]) in ws
//  k_vnb  : vn_feat -> bf16
//  k_nfs  : nfs = node_feat[:,:128] @ w_scalar / sqrt(128) -> bf16
//  k_edge : geometry -> cm MLP (MFMA) -> msg -> vr/rv MLPs (MFMA)
//           -> geometric update; fp32 atomic scatters
//  k_node : fp32 node MLPs, outputs (unchanged from round 2)

#define FEAT 480
#define HDIM 256
#define SDIM 128

typedef __attribute__((ext_vector_type(8))) short bf16x8;
typedef __attribute__((ext_vector_type(4))) float f32x4;

__device__ __forceinline__ float silu_f(float x) {
    return x / (1.0f + __expf(-x));
}
__device__ __forceinline__ ushort f2b(float v) {
    __hip_bfloat16 h = __float2bfloat16(v);
    return *(ushort*)&h;
}

// ---------------------------------------------------------------- k_wprep
// Transposed bf16 weights: w1t[256][416] (pad k>=400 -> 0), w2t/vrw1t/rvw1t
// [256][256], vrw2t[16][256] (rows>=4 zero), rvw2t[16][256].
__global__ __launch_bounds__(256) void k_wprep(
    const float* __restrict__ w1, const float* __restrict__ w2,
    const float* __restrict__ vrw1, const float* __restrict__ rvw1,
    const float* __restrict__ vrw2, const float* __restrict__ rvw2,
    ushort* __restrict__ w1t, ushort* __restrict__ w2t,
    ushort* __restrict__ vrw1t, ushort* __restrict__ rvw1t,
    ushort* __restrict__ vrw2t, ushort* __restrict__ rvw2t)
{
    const int idx = blockIdx.x * 256 + threadIdx.x;
    const int S1 = 256 * 416, S2 = 256 * 256;
    if (idx < S1) {
        const int n = idx / 416, k = idx % 416;
        w1t[idx] = (k < 400) ? f2b(w1[(size_t)k * 256 + n]) : (ushort)0;
    } else if (idx < S1 + S2) {
        const int o = idx - S1, n = o >> 8, k = o & 255;
        w2t[o] = f2b(w2[(size_t)k * 256 + n]);
    } else if (idx < S1 + 2 * S2) {
        const int o = idx - S1 - S2, n = o >> 8, k = o & 255;
        vrw1t[o] = f2b(vrw1[(size_t)k * 256 + n]);
    } else if (idx < S1 + 3 * S2) {
        const int o = idx - S1 - 2 * S2, n = o >> 8, k = o & 255;
        rvw1t[o] = f2b(rvw1[(size_t)k * 256 + n]);
    } else if (idx < S1 + 3 * S2 + 4096) {
        const int o = idx - S1 - 3 * S2, c = o >> 8, k = o & 255;
        vrw2t[o] = (c < 4) ? f2b(vrw2[(size_t)k * 4 + c]) : (ushort)0;
    } else if (idx < S1 + 3 * S2 + 8192) {
        const int o = idx - S1 - 3 * S2 - 4096, c = o >> 8, k = o & 255;
        rvw2t[o] = f2b(rvw2[(size_t)k * 16 + c]);
    }
}

// ---------------------------------------------------------------- k_vnb
__global__ __launch_bounds__(256) void k_vnb(
    const float* __restrict__ vn_feat, ushort* __restrict__ vnb, int total4)
{
    const int i = blockIdx.x * 256 + threadIdx.x;
    if (i >= total4) return;
    const float4 v = *(const float4*)&vn_feat[(size_t)i * 4];
    ushort4 o;
    o.x = f2b(v.x); o.y = f2b(v.y); o.z = f2b(v.z); o.w = f2b(v.w);
    *(ushort4*)&vnb[(size_t)i * 4] = o;
}

// ---------------------------------------------------------------- k_nfs
__global__ __launch_bounds__(256) void k_nfs(
    const float* __restrict__ node_feat, const float* __restrict__ w_scalar,
    ushort* __restrict__ nfsb)
{
    __shared__ float At[32][20];
    __shared__ float Wt[16][128];
    const int t  = threadIdx.x;
    const int m0 = blockIdx.x * 32;
    const int c4 = (t & 31) * 4;
    const int rg = t >> 5;                    // rows rg*4+j
    float acc[4][4] = {};
    for (int k0 = 0; k0 < 128; k0 += 16) {
        if (t < 128) {
            const int r = t >> 2, kk = (t & 3) * 4;
            *(float4*)&At[r][kk] =
                *(const float4*)&node_feat[(size_t)(m0 + r) * FEAT + k0 + kk];
        }
        #pragma unroll
        for (int i = 0; i < 2; ++i) {
            const int p  = t + i * 256;
            const int wr = p >> 5, wc = (p & 31) * 4;
            *(float4*)&Wt[wr][wc] =
                *(const float4*)&w_scalar[(size_t)(k0 + wr) * SDIM + wc];
        }
        __syncthreads();
        #pragma unroll
        for (int kk = 0; kk < 16; ++kk) {
            const float4 w = *(const float4*)&Wt[kk][c4];
            #pragma unroll
            for (int j = 0; j < 4; ++j) {
                const float a = At[rg * 4 + j][kk];
                acc[j][0] = fmaf(a, w.x, acc[j][0]);
                acc[j][1] = fmaf(a, w.y, acc[j][1]);
                acc[j][2] = fmaf(a, w.z, acc[j][2]);
                acc[j][3] = fmaf(a, w.w, acc[j][3]);
            }
        }
        __syncthreads();
    }
    const float s = 0.08838834764831845f;     // 1/sqrt(128)
    #pragma unroll
    for (int j = 0; j < 4; ++j) {
        ushort4 o;
        o.x = f2b(acc[j][0] * s); o.y = f2b(acc[j][1] * s);
        o.z = f2b(acc[j][2] * s); o.w = f2b(acc[j][3] * s);
        *(ushort4*)&nfsb[(size_t)(m0 + rg * 4 + j) * SDIM + c4] = o;
    }
}

// ---------------------------------------------------------------- k_edge
// 32 edges/block, 256 threads = 4 waves. Each wave: rows 0..31 (2 m-tiles),
// cols wv*64..wv*64+63 (4 n-tiles). A in LDS bf16; B direct from L2 (bf16,
// transposed). No barriers inside K-loops.
#define ASTR0 424     // B0 row stride (elems): 848B = 20 mod 32 dwords
#define ASTR1 264     // B1 row stride: 528B = 4 mod 32 dwords

__global__ __launch_bounds__(256) void k_edge(
    const ushort* __restrict__ nfsb, const ushort* __restrict__ vnb,
    const float* __restrict__ node_pos, const float* __restrict__ vn_pos,
    const int* __restrict__ eidx,
    const ushort* __restrict__ w1t, const float* __restrict__ b1,
    const ushort* __restrict__ w2t, const float* __restrict__ b2,
    const ushort* __restrict__ vrw1t, const float* __restrict__ vrb1,
    const ushort* __restrict__ vrw2t, const float* __restrict__ vrb2,
    const ushort* __restrict__ rvw1t, const float* __restrict__ rvb1,
    const ushort* __restrict__ rvw2t, const float* __restrict__ rvb2,
    float* __restrict__ agg_feat, float* __restrict__ agg_vr,
    float* __restrict__ agg_rv, float* __restrict__ cnt, int E)
{
    __shared__ ushort B0[32 * ASTR0];   // 27,136 B: cm A, then msg
    __shared__ ushort B1[32 * ASTR1];   // 16,896 B: hidden buffers
    __shared__ float ipS[32][16];
    __shared__ float dnS[32][12];
    __shared__ float wvrS[32][4];
    __shared__ float wrvS[32][16];
    __shared__ int rowi[32], coli[32];

    const int t  = threadIdx.x;
    const int e0 = blockIdx.x * 32;
    const int wv = t >> 6;
    const int lane = t & 63;
    const int lr = lane & 15;           // row (A), col (B/D)
    const int lk = lane >> 4;           // k-group / D row-group
    const int colBase = wv * 64;

    // ---- geometry ----
    if (t < 32) {
        const int r = eidx[e0 + t];
        const int c = eidx[E + e0 + t];
        rowi[t] = r; coli[t] = c;
        const float px = node_pos[r * 3 + 0];
        const float py = node_pos[r * 3 + 1];
        const float pz = node_pos[r * 3 + 2];
        float d[4][3];
        #pragma unroll
        for (int ch = 0; ch < 4; ++ch) {
            d[ch][0] = px - vn_pos[(size_t)c * 12 + ch * 3 + 0];
            d[ch][1] = py - vn_pos[(size_t)c * 12 + ch * 3 + 1];
            d[ch][2] = pz - vn_pos[(size_t)c * 12 + ch * 3 + 2];
        }
        float ss = 0.f, ipv[16];
        #pragma unroll
        for (int ci = 0; ci < 4; ++ci)
            #pragma unroll
            for (int ck = 0; ck < 4; ++ck) {
                const float v = d[ci][0]*d[ck][0] + d[ci][1]*d[ck][1] + d[ci][2]*d[ck][2];
                ipv[ci * 4 + ck] = v; ss += v * v;
            }
        const float inrm = 1.0f / fmaxf(sqrtf(ss), 1e-8f);
        #pragma unroll
        for (int i = 0; i < 16; ++i) ipS[t][i] = ipv[i] * inrm;
        #pragma unroll
        for (int ch = 0; ch < 4; ++ch) {
            const float nn = sqrtf(d[ch][0]*d[ch][0] + d[ch][1]*d[ch][1] + d[ch][2]*d[ch][2]);
            const float s = 1.0f / fmaxf(nn, 1e-8f);
            dnS[t][ch * 3 + 0] = d[ch][0] * s;
            dnS[t][ch * 3 + 1] = d[ch][1] * s;
            dnS[t][ch * 3 + 2] = d[ch][2] * s;
        }
        atomicAdd(&cnt[r], 1.0f);
    }
    __syncthreads();

    // ---- gather A: [nfs(128) | vn_feat(256) | ip(16) | pad(16)] bf16 ----
    for (int c = t; c < 32 * 52; c += 256) {
        const int r = c / 52, cc = c % 52;
        ushort* dst = &B0[r * ASTR0 + cc * 8];
        if (cc < 16) {
            *(uint4*)dst = *(const uint4*)&nfsb[(size_t)rowi[r] * SDIM + cc * 8];
        } else if (cc < 48) {
            *(uint4*)dst = *(const uint4*)&vnb[(size_t)coli[r] * HDIM + cc * 8 - 128];
        } else if (cc < 50) {
            const int o = (cc - 48) * 8;
            #pragma unroll
            for (int i = 0; i < 8; ++i) dst[i] = f2b(ipS[r][o + i]);
        } else {
            *(uint4*)dst = uint4{0, 0, 0, 0};
        }
    }
    __syncthreads();

    f32x4 acc[2][4];

#define KLOOP(KSTEPS, ABASE, ASTR, WBASE, WSTR)                               \
    {                                                                          \
        _Pragma("unroll")                                                      \
        for (int mt = 0; mt < 2; ++mt)                                         \
            _Pragma("unroll")                                                  \
            for (int nt = 0; nt < 4; ++nt) acc[mt][nt] = (f32x4)0.f;           \
        for (int ks = 0; ks < (KSTEPS); ++ks) {                                \
            const int k0 = ks * 32 + lk * 8;                                   \
            const bf16x8 a0 = *(const bf16x8*)&(ABASE)[lr * (ASTR) + k0];      \
            const bf16x8 a1 = *(const bf16x8*)&(ABASE)[(lr + 16) * (ASTR) + k0]; \
            _Pragma("unroll")                                                  \
            for (int nt = 0; nt < 4; ++nt) {                                   \
                const int col = colBase + nt * 16 + lr;                        \
                const bf16x8 b = *(const bf16x8*)&(WBASE)[(size_t)col * (WSTR) + k0]; \
                acc[0][nt] = __builtin_amdgcn_mfma_f32_16x16x32_bf16(a0, b, acc[0][nt], 0, 0, 0); \
                acc[1][nt] = __builtin_amdgcn_mfma_f32_16x16x32_bf16(a1, b, acc[1][nt], 0, 0, 0); \
            }                                                                  \
        }                                                                      \
    }

    // ===== cm layer 1 (K=416 padded) =====
    KLOOP(13, B0, ASTR0, w1t, 416);
    #pragma unroll
    for (int nt = 0; nt < 4; ++nt) {
        const int col = colBase + nt * 16 + lr;
        const float bb = b1[col];
        #pragma unroll
        for (int mt = 0; mt < 2; ++mt)
            #pragma unroll
            for (int r = 0; r < 4; ++r) {
                const int row = mt * 16 + lk * 4 + r;
                B1[row * ASTR1 + col] = f2b(silu_f(acc[mt][nt][r] + bb));
            }
    }
    __syncthreads();

    // ===== cm layer 2 (K=256) -> msg =====
    KLOOP(8, B1, ASTR1, w2t, 256);
    #pragma unroll
    for (int nt = 0; nt < 4; ++nt) {
        const int col = colBase + nt * 16 + lr;
        const float bb = b2[col];
        #pragma unroll
        for (int mt = 0; mt < 2; ++mt)
            #pragma unroll
            for (int r = 0; r < 4; ++r) {
                const int row = mt * 16 + lk * 4 + r;
                const float m = acc[mt][nt][r] + bb;
                B0[row * ASTR0 + col] = f2b(m);
                atomicAdd(&agg_feat[(size_t)rowi[row] * HDIM + col], m);
            }
    }
    __syncthreads();

    // ===== vr layer 1 (K=256) =====
    KLOOP(8, B0, ASTR0, vrw1t, 256);
    #pragma unroll
    for (int nt = 0; nt < 4; ++nt) {
        const int col = colBase + nt * 16 + lr;
        const float bb = vrb1[col];
        #pragma unroll
        for (int mt = 0; mt < 2; ++mt)
            #pragma unroll
            for (int r = 0; r < 4; ++r) {
                const int row = mt * 16 + lk * 4 + r;
                B1[row * ASTR1 + col] = f2b(silu_f(acc[mt][nt][r] + bb));
            }
    }
    __syncthreads();

    // ===== vr layer 2 (N=4 in one padded 16-col tile, wave 0) =====
    if (wv == 0) {
        f32x4 a2[2]; a2[0] = (f32x4)0.f; a2[1] = (f32x4)0.f;
        for (int ks = 0; ks < 8; ++ks) {
            const int k0 = ks * 32 + lk * 8;
            const bf16x8 a0 = *(const bf16x8*)&B1[lr * ASTR1 + k0];
            const bf16x8 a1 = *(const bf16x8*)&B1[(lr + 16) * ASTR1 + k0];
            const bf16x8 b  = *(const bf16x8*)&vrw2t[(size_t)lr * 256 + k0];
            a2[0] = __builtin_amdgcn_mfma_f32_16x16x32_bf16(a0, b, a2[0], 0, 0, 0);
            a2[1] = __builtin_amdgcn_mfma_f32_16x16x32_bf16(a1, b, a2[1], 0, 0, 0);
        }
        if (lr < 4) {
            const float bb = vrb2[lr];
            #pragma unroll
            for (int mt = 0; mt < 2; ++mt)
                #pragma unroll
                for (int r = 0; r < 4; ++r)
                    wvrS[mt * 16 + lk * 4 + r][lr] = a2[mt][r] + bb;
        }
    }
    __syncthreads();

    // ===== rv layer 1 (K=256) =====
    KLOOP(8, B0, ASTR0, rvw1t, 256);
    #pragma unroll
    for (int nt = 0; nt < 4; ++nt) {
        const int col = colBase + nt * 16 + lr;
        const float bb = rvb1[col];
        #pragma unroll
        for (int mt = 0; mt < 2; ++mt)
            #pragma unroll
            for (int r = 0; r < 4; ++r) {
                const int row = mt * 16 + lk * 4 + r;
                B1[row * ASTR1 + col] = f2b(silu_f(acc[mt][nt][r] + bb));
            }
    }
    __syncthreads();

    // ===== rv layer 2 (N=16, wave 0) =====
    if (wv == 0) {
        f32x4 a2[2]; a2[0] = (f32x4)0.f; a2[1] = (f32x4)0.f;
        for (int ks = 0; ks < 8; ++ks) {
            const int k0 = ks * 32 + lk * 8;
            const bf16x8 a0 = *(const bf16x8*)&B1[lr * ASTR1 + k0];
            const bf16x8 a1 = *(const bf16x8*)&B1[(lr + 16) * ASTR1 + k0];
            const bf16x8 b  = *(const bf16x8*)&rvw2t[(size_t)lr * 256 + k0];
            a2[0] = __builtin_amdgcn_mfma_f32_16x16x32_bf16(a0, b, a2[0], 0, 0, 0);
            a2[1] = __builtin_amdgcn_mfma_f32_16x16x32_bf16(a1, b, a2[1], 0, 0, 0);
        }
        const float bb = rvb2[lr];
        #pragma unroll
        for (int mt = 0; mt < 2; ++mt)
            #pragma unroll
            for (int r = 0; r < 4; ++r)
                wrvS[mt * 16 + lk * 4 + r][lr] = a2[mt][r] + bb;
    }
    __syncthreads();

    // ===== geometric update + scatter (t<32) =====
    if (t < 32) {
        const int rr = rowi[t];
        float dn[12];
        #pragma unroll
        for (int i = 0; i < 12; ++i) dn[i] = dnS[t][i];
        #pragma unroll
        for (int j = 0; j < 3; ++j) {
            float v = 0.f;
            #pragma unroll
            for (int c = 0; c < 4; ++c) v = fmaf(wvrS[t][c], dn[c * 3 + j], v);
            atomicAdd(&agg_vr[(size_t)rr * 3 + j], 0.5f * v);     // inv = 1/sqrt(4)
        }
        #pragma unroll
        for (int u = 0; u < 4; ++u)
            #pragma unroll
            for (int j = 0; j < 3; ++j) {
                float v = 0.f;
                #pragma unroll
                for (int c = 0; c < 4; ++c) v = fmaf(wrvS[t][c * 4 + u], dn[c * 3 + j], v);
                atomicAdd(&agg_rv[(size_t)rr * 12 + u * 3 + j], -0.5f * v);
            }
    }
#undef KLOOP
}

// ---------------------------------------------------------------- k_node helpers
__device__ __forceinline__ void gemm16x256(
    const float Ab[16][260], float Wt[16][256], const float* __restrict__ Wsrc,
    float acc[4][4], const int t, const int c4, const int rg)
{
    #pragma unroll
    for (int j = 0; j < 4; ++j) { acc[j][0]=0.f; acc[j][1]=0.f; acc[j][2]=0.f; acc[j][3]=0.f; }
    for (int k0 = 0; k0 < 256; k0 += 16) {
        #pragma unroll
        for (int i = 0; i < 4; ++i) {
            const int p  = t + i * 256;
            const int wr = p >> 6, wc = (p & 63) * 4;
            *(float4*)&Wt[wr][wc] = *(const float4*)&Wsrc[(size_t)(k0 + wr) * 256 + wc];
        }
        __syncthreads();
        #pragma unroll
        for (int kk = 0; kk < 16; ++kk) {
            const float4 w = *(const float4*)&Wt[kk][c4];
            #pragma unroll
            for (int j = 0; j < 4; ++j) {
                const float a = Ab[rg * 4 + j][k0 + kk];
                acc[j][0] = fmaf(a, w.x, acc[j][0]); acc[j][1] = fmaf(a, w.y, acc[j][1]);
                acc[j][2] = fmaf(a, w.z, acc[j][2]); acc[j][3] = fmaf(a, w.w, acc[j][3]);
            }
        }
        __syncthreads();
    }
}

// ---------------------------------------------------------------- k_node
__global__ __launch_bounds__(256) void k_node(
    const float* __restrict__ node_feat, const float* __restrict__ node_pos,
    const float* __restrict__ vn_feat, const float* __restrict__ vn_pos,
    const float* __restrict__ agg_feat, const float* __restrict__ agg_vr,
    const float* __restrict__ agg_rv, const float* __restrict__ cnt,
    const float* __restrict__ ftw1, const float* __restrict__ ftb1,
    const float* __restrict__ ftw2, const float* __restrict__ ftb2,
    const float* __restrict__ f2tw1, const float* __restrict__ f2tb1,
    const float* __restrict__ f2tw2, const float* __restrict__ f2tb2,
    const float* __restrict__ vfw1, const float* __restrict__ vfb1,
    const float* __restrict__ vfw2, const float* __restrict__ vfb2,
    float* __restrict__ out, int Nn)
{
    __shared__ float At[16][260];
    __shared__ float Ht[16][260];
    __shared__ float Wt[16][256];
    __shared__ float rc[16];
    const int t  = threadIdx.x;
    const int n0 = blockIdx.x * 16;
    float* nf_out = out;
    float* np_out = out + (size_t)Nn * FEAT;
    float* vf_out = np_out + (size_t)Nn * 3;
    float* vp_out = vf_out + (size_t)Nn * HDIM;

    if (t < 16) rc[t] = 1.0f / fmaxf(cnt[n0 + t], 1.0f);
    __syncthreads();
    #pragma unroll
    for (int i = 0; i < 4; ++i) {
        const int p = t + i * 256;
        const int r = p >> 6, cc = (p & 63) * 4;
        float4 v = *(const float4*)&agg_feat[(size_t)(n0 + r) * HDIM + cc];
        const float s = rc[r];
        v.x *= s; v.y *= s; v.z *= s; v.w *= s;
        *(float4*)&At[r][cc] = v;
    }
    __syncthreads();
    const int c4 = (t & 63) * 4;
    const int rg = t >> 6;
    float acc[4][4];

    // ---- vf MLP ----
    gemm16x256(At, Wt, vfw1, acc, t, c4, rg);
    {
        const float4 bb = *(const float4*)&vfb1[c4];
        #pragma unroll
        for (int j = 0; j < 4; ++j) {
            float4 h;
            h.x = silu_f(acc[j][0] + bb.x); h.y = silu_f(acc[j][1] + bb.y);
            h.z = silu_f(acc[j][2] + bb.z); h.w = silu_f(acc[j][3] + bb.w);
            *(float4*)&Ht[rg * 4 + j][c4] = h;
        }
    }
    __syncthreads();
    gemm16x256(Ht, Wt, vfw2, acc, t, c4, rg);
    {
        const float4 bb = *(const float4*)&vfb2[c4];
        #pragma unroll
        for (int j = 0; j < 4; ++j) {
            const int r = rg * 4 + j;
            float4 v = *(const float4*)&vn_feat[(size_t)(n0 + r) * HDIM + c4];
            v.x += acc[j][0] + bb.x; v.y += acc[j][1] + bb.y;
            v.z += acc[j][2] + bb.z; v.w += acc[j][3] + bb.w;
            *(float4*)&vf_out[(size_t)(n0 + r) * HDIM + c4] = v;
        }
    }

    // ---- ft MLP ----
    gemm16x256(At, Wt, ftw1, acc, t, c4, rg);
    {
        const float4 bb = *(const float4*)&ftb1[c4];
        #pragma unroll
        for (int j = 0; j < 4; ++j) {
            float4 h;
            h.x = silu_f(acc[j][0] + bb.x); h.y = silu_f(acc[j][1] + bb.y);
            h.z = silu_f(acc[j][2] + bb.z); h.w = silu_f(acc[j][3] + bb.w);
            *(float4*)&Ht[rg * 4 + j][c4] = h;
        }
    }
    __syncthreads();
    gemm16x256(Ht, Wt, ftw2, acc, t, c4, rg);
    {
        const float4 bb = *(const float4*)&ftb2[c4];
        #pragma unroll
        for (int j = 0; j < 4; ++j) {
            float4 v;
            v.x = acc[j][0] + bb.x; v.y = acc[j][1] + bb.y;
            v.z = acc[j][2] + bb.z; v.w = acc[j][3] + bb.w;
            *(float4*)&At[rg * 4 + j][c4] = v;
        }
    }
    __syncthreads();

    // ---- f2t MLP ----
    gemm16x256(At, Wt, f2tw1, acc, t, c4, rg);
    {
        const float4 bb = *(const float4*)&f2tb1[c4];
        #pragma unroll
        for (int j = 0; j < 4; ++j) {
            float4 h;
            h.x = silu_f(acc[j][0] + bb.x); h.y = silu_f(acc[j][1] + bb.y);
            h.z = silu_f(acc[j][2] + bb.z); h.w = silu_f(acc[j][3] + bb.w);
            *(float4*)&Ht[rg * 4 + j][c4] = h;
        }
    }
    __syncthreads();
    {   // layer 2, N=128: ds + residual
        const int c4b = (t & 31) * 4;
        const int rgb = t >> 5;
        float* Wfl = &Wt[0][0];
        float a3[2][4] = {};
        for (int k0 = 0; k0 < 256; k0 += 16) {
            #pragma unroll
            for (int i = 0; i < 2; ++i) {
                const int p  = t + i * 256;
                const int wr = p >> 5, wc = (p & 31) * 4;
                *(float4*)&Wfl[wr * 128 + wc] =
                    *(const float4*)&f2tw2[(size_t)(k0 + wr) * SDIM + wc];
            }
            __syncthreads();
            #pragma unroll
            for (int kk = 0; kk < 16; ++kk) {
                const float4 w = *(const float4*)&Wfl[kk * 128 + c4b];
                #pragma unroll
                for (int j = 0; j < 2; ++j) {
                    const float a = Ht[rgb * 2 + j][k0 + kk];
                    a3[j][0] = fmaf(a, w.x, a3[j][0]); a3[j][1] = fmaf(a, w.y, a3[j][1]);
                    a3[j][2] = fmaf(a, w.z, a3[j][2]); a3[j][3] = fmaf(a, w.w, a3[j][3]);
                }
            }
            __syncthreads();
        }
        const float4 bb = *(const float4*)&f2tb2[c4b];
        #pragma unroll
        for (int j = 0; j < 2; ++j) {
            const int r = rgb * 2 + j;
            float4 v = *(const float4*)&node_feat[(size_t)(n0 + r) * FEAT + c4b];
            v.x += a3[j][0] + bb.x; v.y += a3[j][1] + bb.y;
            v.z += a3[j][2] + bb.z; v.w += a3[j][3] + bb.w;
            *(float4*)&nf_out[(size_t)(n0 + r) * FEAT + c4b] = v;
        }
    }

    for (int p = t; p < 16 * 352; p += 256) {
        const int r  = p / 352;
        const int cc = 128 + (p % 352);
        nf_out[(size_t)(n0 + r) * FEAT + cc] = node_feat[(size_t)(n0 + r) * FEAT + cc];
    }
    if (t < 16) {
        const int n = n0 + t;
        const float s = rc[t];
        #pragma unroll
        for (int j = 0; j < 3; ++j)
            np_out[(size_t)n * 3 + j] = node_pos[(size_t)n * 3 + j] + agg_vr[(size_t)n * 3 + j] * s;
        #pragma unroll
        for (int j = 0; j < 12; ++j)
            vp_out[(size_t)n * 12 + j] = vn_pos[(size_t)n * 12 + j] + agg_rv[(size_t)n * 12 + j] * s;
    }
}

// ---------------------------------------------------------------- launch
extern "C" void kernel_launch(void* const* d_in, const int* in_sizes, int n_in,
                              void* d_out, int out_size, void* d_ws, size_t ws_size,
                              hipStream_t stream)
{
    (void)n_in; (void)out_size; (void)ws_size;
    const float* node_feat = (const float*)d_in[0];
    const float* node_pos  = (const float*)d_in[1];
    const float* vn_feat   = (const float*)d_in[2];
    const float* vn_pos    = (const float*)d_in[3];
    const int*   eidx      = (const int*)d_in[4];
    const float* w_scalar  = (const float*)d_in[5];
    const float* cm_w1  = (const float*)d_in[6];
    const float* cm_b1  = (const float*)d_in[7];
    const float* cm_w2  = (const float*)d_in[8];
    const float* cm_b2  = (const float*)d_in[9];
    const float* vr_w1  = (const float*)d_in[10];
    const float* vr_b1  = (const float*)d_in[11];
    const float* vr_w2  = (const float*)d_in[12];
    const float* vr_b2  = (const float*)d_in[13];
    const float* rv_w1  = (const float*)d_in[14];
    const float* rv_b1  = (const float*)d_in[15];
    const float* rv_w2  = (const float*)d_in[16];
    const float* rv_b2  = (const float*)d_in[17];
    const float* ft_w1  = (const float*)d_in[18];
    const float* ft_b1  = (const float*)d_in[19];
    const float* ft_w2  = (const float*)d_in[20];
    const float* ft_b2  = (const float*)d_in[21];
    const float* f2t_w1 = (const float*)d_in[22];
    const float* f2t_b1 = (const float*)d_in[23];
    const float* f2t_w2 = (const float*)d_in[24];
    const float* f2t_b2 = (const float*)d_in[25];
    const float* vf_w1  = (const float*)d_in[26];
    const float* vf_b1  = (const float*)d_in[27];
    const float* vf_w2  = (const float*)d_in[28];
    const float* vf_b2  = (const float*)d_in[29];

    const int Nn = in_sizes[0] / FEAT;        // 20000
    const int E  = in_sizes[4] / 2;           // 240000

    // workspace: fp32 region then bf16 region (all 16B-aligned)
    float* ws       = (float*)d_ws;
    float* agg_feat = ws;                                // Nn*256
    float* agg_vr   = agg_feat + (size_t)Nn * HDIM;      // Nn*3
    float* agg_rv   = agg_vr   + (size_t)Nn * 3;         // Nn*12
    float* cnt      = agg_rv   + (size_t)Nn * 12;        // Nn
    ushort* nfsb  = (ushort*)(cnt + Nn);                 // Nn*128
    ushort* vnb   = nfsb  + (size_t)Nn * SDIM;           // Nn*256
    ushort* w1t   = vnb   + (size_t)Nn * HDIM;           // 256*416
    ushort* w2t   = w1t   + 256 * 416;                   // 256*256
    ushort* vrw1t = w2t   + 256 * 256;
    ushort* rvw1t = vrw1t + 256 * 256;
    ushort* vrw2t = rvw1t + 256 * 256;                   // 16*256
    ushort* rvw2t = vrw2t + 16 * 256;                    // 16*256

    const size_t zero_bytes = (size_t)Nn * (HDIM + 3 + 12 + 1) * sizeof(float);
    hipMemsetAsync(agg_feat, 0, zero_bytes, stream);

    k_wprep<<<1216, 256, 0, stream>>>(cm_w1, cm_w2, vr_w1, rv_w1, vr_w2, rv_w2,
                                      w1t, w2t, vrw1t, rvw1t, vrw2t, rvw2t);
    k_vnb<<<(Nn * 64 + 255) / 256, 256, 0, stream>>>(vn_feat, vnb, Nn * 64);
    k_nfs<<<Nn / 32, 256, 0, stream>>>(node_feat, w_scalar, nfsb);
    k_edge<<<E / 32, 256, 0, stream>>>(nfsb, vnb, node_pos, vn_pos, eidx,
                                       w1t, cm_b1, w2t, cm_b2,
                                       vrw1t, vr_b1, vrw2t, vr_b2,
                                       rvw1t, rv_b1, rvw2t, rv_b2,
                                       agg_feat, agg_vr, agg_rv, cnt, E);
    k_node<<<Nn / 16, 256, 0, stream>>>(node_feat, node_pos, vn_feat, vn_pos,
                                        agg_feat, agg_vr, agg_rv, cnt,
                                        ft_w1, ft_b1, ft_w2, ft_b2,
                                        f2t_w1, f2t_b1, f2t_w2, f2t_b2,
                                        vf_w1, vf_b1, vf_w2, vf_b2,
                                        (float*)d_out, Nn);
}

// Round 4
// 1020.951 us; speedup vs baseline: 3.1546x; 1.0174x over previous
//
#include <hip/hip_runtime.h>
#include <hip/hip_bf16.h>
#include <math.h>

// VNLayer: N=20000 nodes, E=240000 edges, H=256, SD=128, C=4, FEAT=480
// Round 4: latency-oriented k_edge rewrite.
//  - cm layer-1 A read per-lane DIRECT from global (no LDS A staging)
//  - all K-loops fully unrolled (compile-time ks) -> deep load hoisting
//  - LDS 39.3KB -> 4 blocks/CU; __launch_bounds__(256,4) caps VGPR at 128

#define FEAT 480
#define HDIM 256
#define SDIM 128
#define MSTR 264    // msg/hidden LDS row stride (ushorts): 528B, 2-way max

typedef __attribute__((ext_vector_type(8))) short bf16x8;
typedef __attribute__((ext_vector_type(4))) float f32x4;

__device__ __forceinline__ float silu_f(float x) {
    return x / (1.0f + __expf(-x));
}
__device__ __forceinline__ ushort f2b(float v) {
    __hip_bfloat16 h = __float2bfloat16(v);
    return *(ushort*)&h;
}

// ---------------------------------------------------------------- k_wprep
__global__ __launch_bounds__(256) void k_wprep(
    const float* __restrict__ w1, const float* __restrict__ w2,
    const float* __restrict__ vrw1, const float* __restrict__ rvw1,
    const float* __restrict__ vrw2, const float* __restrict__ rvw2,
    ushort* __restrict__ w1t, ushort* __restrict__ w2t,
    ushort* __restrict__ vrw1t, ushort* __restrict__ rvw1t,
    ushort* __restrict__ vrw2t, ushort* __restrict__ rvw2t)
{
    const int idx = blockIdx.x * 256 + threadIdx.x;
    const int S1 = 256 * 416, S2 = 256 * 256;
    if (idx < S1) {
        const int n = idx / 416, k = idx % 416;
        w1t[idx] = (k < 400) ? f2b(w1[(size_t)k * 256 + n]) : (ushort)0;
    } else if (idx < S1 + S2) {
        const int o = idx - S1, n = o >> 8, k = o & 255;
        w2t[o] = f2b(w2[(size_t)k * 256 + n]);
    } else if (idx < S1 + 2 * S2) {
        const int o = idx - S1 - S2, n = o >> 8, k = o & 255;
        vrw1t[o] = f2b(vrw1[(size_t)k * 256 + n]);
    } else if (idx < S1 + 3 * S2) {
        const int o = idx - S1 - 2 * S2, n = o >> 8, k = o & 255;
        rvw1t[o] = f2b(rvw1[(size_t)k * 256 + n]);
    } else if (idx < S1 + 3 * S2 + 4096) {
        const int o = idx - S1 - 3 * S2, c = o >> 8, k = o & 255;
        vrw2t[o] = (c < 4) ? f2b(vrw2[(size_t)k * 4 + c]) : (ushort)0;
    } else if (idx < S1 + 3 * S2 + 8192) {
        const int o = idx - S1 - 3 * S2 - 4096, c = o >> 8, k = o & 255;
        rvw2t[o] = f2b(rvw2[(size_t)k * 16 + c]);
    }
}

// ---------------------------------------------------------------- k_vnb
__global__ __launch_bounds__(256) void k_vnb(
    const float* __restrict__ vn_feat, ushort* __restrict__ vnb, int total4)
{
    const int i = blockIdx.x * 256 + threadIdx.x;
    if (i >= total4) return;
    const float4 v = *(const float4*)&vn_feat[(size_t)i * 4];
    ushort4 o;
    o.x = f2b(v.x); o.y = f2b(v.y); o.z = f2b(v.z); o.w = f2b(v.w);
    *(ushort4*)&vnb[(size_t)i * 4] = o;
}

// ---------------------------------------------------------------- k_nfs
__global__ __launch_bounds__(256) void k_nfs(
    const float* __restrict__ node_feat, const float* __restrict__ w_scalar,
    ushort* __restrict__ nfsb)
{
    __shared__ float At[32][20];
    __shared__ float Wt[16][128];
    const int t  = threadIdx.x;
    const int m0 = blockIdx.x * 32;
    const int c4 = (t & 31) * 4;
    const int rg = t >> 5;
    float acc[4][4] = {};
    for (int k0 = 0; k0 < 128; k0 += 16) {
        if (t < 128) {
            const int r = t >> 2, kk = (t & 3) * 4;
            *(float4*)&At[r][kk] =
                *(const float4*)&node_feat[(size_t)(m0 + r) * FEAT + k0 + kk];
        }
        #pragma unroll
        for (int i = 0; i < 2; ++i) {
            const int p  = t + i * 256;
            const int wr = p >> 5, wc = (p & 31) * 4;
            *(float4*)&Wt[wr][wc] =
                *(const float4*)&w_scalar[(size_t)(k0 + wr) * SDIM + wc];
        }
        __syncthreads();
        #pragma unroll
        for (int kk = 0; kk < 16; ++kk) {
            const float4 w = *(const float4*)&Wt[kk][c4];
            #pragma unroll
            for (int j = 0; j < 4; ++j) {
                const float a = At[rg * 4 + j][kk];
                acc[j][0] = fmaf(a, w.x, acc[j][0]);
                acc[j][1] = fmaf(a, w.y, acc[j][1]);
                acc[j][2] = fmaf(a, w.z, acc[j][2]);
                acc[j][3] = fmaf(a, w.w, acc[j][3]);
            }
        }
        __syncthreads();
    }
    const float s = 0.08838834764831845f;
    #pragma unroll
    for (int j = 0; j < 4; ++j) {
        ushort4 o;
        o.x = f2b(acc[j][0] * s); o.y = f2b(acc[j][1] * s);
        o.z = f2b(acc[j][2] * s); o.w = f2b(acc[j][3] * s);
        *(ushort4*)&nfsb[(size_t)(m0 + rg * 4 + j) * SDIM + c4] = o;
    }
}

// ---------------------------------------------------------------- k_edge
// 32 edges/block, 256 threads = 4 waves. Wave wv: rows 0..31 (2 m-tiles),
// cols wv*64..+63 (4 n-tiles). cm1 A per-lane from global; msg/hidden in LDS.
__global__ __launch_bounds__(256, 4) void k_edge(
    const ushort* __restrict__ nfsb, const ushort* __restrict__ vnb,
    const float* __restrict__ node_pos, const float* __restrict__ vn_pos,
    const int* __restrict__ eidx,
    const ushort* __restrict__ w1t, const float* __restrict__ b1,
    const ushort* __restrict__ w2t, const float* __restrict__ b2,
    const ushort* __restrict__ vrw1t, const float* __restrict__ vrb1,
    const ushort* __restrict__ vrw2t, const float* __restrict__ vrb2,
    const ushort* __restrict__ rvw1t, const float* __restrict__ rvb1,
    const ushort* __restrict__ rvw2t, const float* __restrict__ rvb2,
    float* __restrict__ agg_feat, float* __restrict__ agg_vr,
    float* __restrict__ agg_rv, float* __restrict__ cnt, int E)
{
    __shared__ ushort Mg[32 * MSTR];   // 16.9 KB msg
    __shared__ ushort Hd[32 * MSTR];   // 16.9 KB hidden
    __shared__ ushort ipB[32 * 32];    // 2 KB  gram bf16 (cols 16..31 zero)
    __shared__ float dnS[32][12];
    __shared__ float wvrS[32][4];
    __shared__ float wrvS[32][16];
    __shared__ int rowi[32], coli[32];

    const int t  = threadIdx.x;
    const int e0 = blockIdx.x * 32;
    const int wv = t >> 6;
    const int lane = t & 63;
    const int lr = lane & 15;
    const int lk = lane >> 4;
    const int colBase = wv * 64;

    // ---- geometry (t<32) ----
    if (t < 32) {
        const int r = eidx[e0 + t];
        const int c = eidx[E + e0 + t];
        rowi[t] = r; coli[t] = c;
        const float px = node_pos[r * 3 + 0];
        const float py = node_pos[r * 3 + 1];
        const float pz = node_pos[r * 3 + 2];
        float d[4][3];
        #pragma unroll
        for (int ch = 0; ch < 4; ++ch) {
            d[ch][0] = px - vn_pos[(size_t)c * 12 + ch * 3 + 0];
            d[ch][1] = py - vn_pos[(size_t)c * 12 + ch * 3 + 1];
            d[ch][2] = pz - vn_pos[(size_t)c * 12 + ch * 3 + 2];
        }
        float ss = 0.f, ipv[16];
        #pragma unroll
        for (int ci = 0; ci < 4; ++ci)
            #pragma unroll
            for (int ck = 0; ck < 4; ++ck) {
                const float v = d[ci][0]*d[ck][0] + d[ci][1]*d[ck][1] + d[ci][2]*d[ck][2];
                ipv[ci * 4 + ck] = v; ss += v * v;
            }
        const float inrm = 1.0f / fmaxf(sqrtf(ss), 1e-8f);
        #pragma unroll
        for (int i = 0; i < 16; ++i) ipB[t * 32 + i] = f2b(ipv[i] * inrm);
        #pragma unroll
        for (int i = 16; i < 32; ++i) ipB[t * 32 + i] = 0;
        #pragma unroll
        for (int ch = 0; ch < 4; ++ch) {
            const float nn = sqrtf(d[ch][0]*d[ch][0] + d[ch][1]*d[ch][1] + d[ch][2]*d[ch][2]);
            const float s = 1.0f / fmaxf(nn, 1e-8f);
            dnS[t][ch * 3 + 0] = d[ch][0] * s;
            dnS[t][ch * 3 + 1] = d[ch][1] * s;
            dnS[t][ch * 3 + 2] = d[ch][2] * s;
        }
        atomicAdd(&cnt[r], 1.0f);
    }
    __syncthreads();

    // per-lane A row bases for cm1 direct-global reads
    const ushort* nA0 = nfsb + (size_t)rowi[lr]      * SDIM + lk * 8;
    const ushort* nA1 = nfsb + (size_t)rowi[lr + 16] * SDIM + lk * 8;
    const ushort* vA0 = vnb  + (size_t)coli[lr]      * HDIM + lk * 8;
    const ushort* vA1 = vnb  + (size_t)coli[lr + 16] * HDIM + lk * 8;

    f32x4 acc[2][4];
    #pragma unroll
    for (int mt = 0; mt < 2; ++mt)
        #pragma unroll
        for (int nt = 0; nt < 4; ++nt) acc[mt][nt] = (f32x4)0.f;

    // ===== cm layer 1 (K=416: 128 nfs | 256 vn | 32 ip/pad) =====
    #pragma unroll
    for (int ks = 0; ks < 13; ++ks) {
        bf16x8 a0, a1;
        if (ks < 4) {
            a0 = *(const bf16x8*)(nA0 + ks * 32);
            a1 = *(const bf16x8*)(nA1 + ks * 32);
        } else if (ks < 12) {
            a0 = *(const bf16x8*)(vA0 + ks * 32 - 128);
            a1 = *(const bf16x8*)(vA1 + ks * 32 - 128);
        } else {
            a0 = *(const bf16x8*)&ipB[lr * 32 + lk * 8];
            a1 = *(const bf16x8*)&ipB[(lr + 16) * 32 + lk * 8];
        }
        #pragma unroll
        for (int nt = 0; nt < 4; ++nt) {
            const bf16x8 b = *(const bf16x8*)&w1t[(size_t)(colBase + nt * 16 + lr) * 416 + ks * 32 + lk * 8];
            acc[0][nt] = __builtin_amdgcn_mfma_f32_16x16x32_bf16(a0, b, acc[0][nt], 0, 0, 0);
            acc[1][nt] = __builtin_amdgcn_mfma_f32_16x16x32_bf16(a1, b, acc[1][nt], 0, 0, 0);
        }
    }
    #pragma unroll
    for (int nt = 0; nt < 4; ++nt) {
        const int col = colBase + nt * 16 + lr;
        const float bb = b1[col];
        #pragma unroll
        for (int mt = 0; mt < 2; ++mt)
            #pragma unroll
            for (int r = 0; r < 4; ++r) {
                const int row = mt * 16 + lk * 4 + r;
                Hd[row * MSTR + col] = f2b(silu_f(acc[mt][nt][r] + bb));
            }
    }
    __syncthreads();

#define KLOOP_LDS(SRC, WBASE)                                                  \
    {                                                                          \
        _Pragma("unroll")                                                      \
        for (int mt = 0; mt < 2; ++mt)                                         \
            _Pragma("unroll")                                                  \
            for (int nt = 0; nt < 4; ++nt) acc[mt][nt] = (f32x4)0.f;           \
        _Pragma("unroll")                                                      \
        for (int ks = 0; ks < 8; ++ks) {                                       \
            const bf16x8 a0 = *(const bf16x8*)&(SRC)[lr * MSTR + ks * 32 + lk * 8];        \
            const bf16x8 a1 = *(const bf16x8*)&(SRC)[(lr + 16) * MSTR + ks * 32 + lk * 8]; \
            _Pragma("unroll")                                                  \
            for (int nt = 0; nt < 4; ++nt) {                                   \
                const bf16x8 b = *(const bf16x8*)&(WBASE)[(size_t)(colBase + nt * 16 + lr) * 256 + ks * 32 + lk * 8]; \
                acc[0][nt] = __builtin_amdgcn_mfma_f32_16x16x32_bf16(a0, b, acc[0][nt], 0, 0, 0); \
                acc[1][nt] = __builtin_amdgcn_mfma_f32_16x16x32_bf16(a1, b, acc[1][nt], 0, 0, 0); \
            }                                                                  \
        }                                                                      \
    }

    // ===== cm layer 2 -> msg (Mg) + agg_feat scatter =====
    KLOOP_LDS(Hd, w2t);
    #pragma unroll
    for (int nt = 0; nt < 4; ++nt) {
        const int col = colBase + nt * 16 + lr;
        const float bb = b2[col];
        #pragma unroll
        for (int mt = 0; mt < 2; ++mt)
            #pragma unroll
            for (int r = 0; r < 4; ++r) {
                const int row = mt * 16 + lk * 4 + r;
                const float m = acc[mt][nt][r] + bb;
                Mg[row * MSTR + col] = f2b(m);
                atomicAdd(&agg_feat[(size_t)rowi[row] * HDIM + col], m);
            }
    }
    __syncthreads();

    // ===== vr layer 1 =====
    KLOOP_LDS(Mg, vrw1t);
    #pragma unroll
    for (int nt = 0; nt < 4; ++nt) {
        const int col = colBase + nt * 16 + lr;
        const float bb = vrb1[col];
        #pragma unroll
        for (int mt = 0; mt < 2; ++mt)
            #pragma unroll
            for (int r = 0; r < 4; ++r) {
                const int row = mt * 16 + lk * 4 + r;
                Hd[row * MSTR + col] = f2b(silu_f(acc[mt][nt][r] + bb));
            }
    }
    __syncthreads();

    // ===== vr layer 2 (wave 0, N=4 padded to 16) =====
    if (wv == 0) {
        f32x4 a2[2]; a2[0] = (f32x4)0.f; a2[1] = (f32x4)0.f;
        #pragma unroll
        for (int ks = 0; ks < 8; ++ks) {
            const bf16x8 a0 = *(const bf16x8*)&Hd[lr * MSTR + ks * 32 + lk * 8];
            const bf16x8 a1 = *(const bf16x8*)&Hd[(lr + 16) * MSTR + ks * 32 + lk * 8];
            const bf16x8 b  = *(const bf16x8*)&vrw2t[(size_t)lr * 256 + ks * 32 + lk * 8];
            a2[0] = __builtin_amdgcn_mfma_f32_16x16x32_bf16(a0, b, a2[0], 0, 0, 0);
            a2[1] = __builtin_amdgcn_mfma_f32_16x16x32_bf16(a1, b, a2[1], 0, 0, 0);
        }
        if (lr < 4) {
            const float bb = vrb2[lr];
            #pragma unroll
            for (int mt = 0; mt < 2; ++mt)
                #pragma unroll
                for (int r = 0; r < 4; ++r)
                    wvrS[mt * 16 + lk * 4 + r][lr] = a2[mt][r] + bb;
        }
    }
    __syncthreads();

    // ===== rv layer 1 =====
    KLOOP_LDS(Mg, rvw1t);
    #pragma unroll
    for (int nt = 0; nt < 4; ++nt) {
        const int col = colBase + nt * 16 + lr;
        const float bb = rvb1[col];
        #pragma unroll
        for (int mt = 0; mt < 2; ++mt)
            #pragma unroll
            for (int r = 0; r < 4; ++r) {
                const int row = mt * 16 + lk * 4 + r;
                Hd[row * MSTR + col] = f2b(silu_f(acc[mt][nt][r] + bb));
            }
    }
    __syncthreads();

    // ===== rv layer 2 (wave 0, N=16) =====
    if (wv == 0) {
        f32x4 a2[2]; a2[0] = (f32x4)0.f; a2[1] = (f32x4)0.f;
        #pragma unroll
        for (int ks = 0; ks < 8; ++ks) {
            const bf16x8 a0 = *(const bf16x8*)&Hd[lr * MSTR + ks * 32 + lk * 8];
            const bf16x8 a1 = *(const bf16x8*)&Hd[(lr + 16) * MSTR + ks * 32 + lk * 8];
            const bf16x8 b  = *(const bf16x8*)&rvw2t[(size_t)lr * 256 + ks * 32 + lk * 8];
            a2[0] = __builtin_amdgcn_mfma_f32_16x16x32_bf16(a0, b, a2[0], 0, 0, 0);
            a2[1] = __builtin_amdgcn_mfma_f32_16x16x32_bf16(a1, b, a2[1], 0, 0, 0);
        }
        const float bb = rvb2[lr];
        #pragma unroll
        for (int mt = 0; mt < 2; ++mt)
            #pragma unroll
            for (int r = 0; r < 4; ++r)
                wrvS[mt * 16 + lk * 4 + r][lr] = a2[mt][r] + bb;
    }
    __syncthreads();

    // ===== geometric update + scatter (t<32) =====
    if (t < 32) {
        const int rr = rowi[t];
        float dn[12];
        #pragma unroll
        for (int i = 0; i < 12; ++i) dn[i] = dnS[t][i];
        #pragma unroll
        for (int j = 0; j < 3; ++j) {
            float v = 0.f;
            #pragma unroll
            for (int c = 0; c < 4; ++c) v = fmaf(wvrS[t][c], dn[c * 3 + j], v);
            atomicAdd(&agg_vr[(size_t)rr * 3 + j], 0.5f * v);
        }
        #pragma unroll
        for (int u = 0; u < 4; ++u)
            #pragma unroll
            for (int j = 0; j < 3; ++j) {
                float v = 0.f;
                #pragma unroll
                for (int c = 0; c < 4; ++c) v = fmaf(wrvS[t][c * 4 + u], dn[c * 3 + j], v);
                atomicAdd(&agg_rv[(size_t)rr * 12 + u * 3 + j], -0.5f * v);
            }
    }
#undef KLOOP_LDS
}

// ---------------------------------------------------------------- k_node helpers
__device__ __forceinline__ void gemm16x256(
    const float Ab[16][260], float Wt[16][256], const float* __restrict__ Wsrc,
    float acc[4][4], const int t, const int c4, const int rg)
{
    #pragma unroll
    for (int j = 0; j < 4; ++j) { acc[j][0]=0.f; acc[j][1]=0.f; acc[j][2]=0.f; acc[j][3]=0.f; }
    for (int k0 = 0; k0 < 256; k0 += 16) {
        #pragma unroll
        for (int i = 0; i < 4; ++i) {
            const int p  = t + i * 256;
            const int wr = p >> 6, wc = (p & 63) * 4;
            *(float4*)&Wt[wr][wc] = *(const float4*)&Wsrc[(size_t)(k0 + wr) * 256 + wc];
        }
        __syncthreads();
        #pragma unroll
        for (int kk = 0; kk < 16; ++kk) {
            const float4 w = *(const float4*)&Wt[kk][c4];
            #pragma unroll
            for (int j = 0; j < 4; ++j) {
                const float a = Ab[rg * 4 + j][k0 + kk];
                acc[j][0] = fmaf(a, w.x, acc[j][0]); acc[j][1] = fmaf(a, w.y, acc[j][1]);
                acc[j][2] = fmaf(a, w.z, acc[j][2]); acc[j][3] = fmaf(a, w.w, acc[j][3]);
            }
        }
        __syncthreads();
    }
}

// ---------------------------------------------------------------- k_node
__global__ __launch_bounds__(256) void k_node(
    const float* __restrict__ node_feat, const float* __restrict__ node_pos,
    const float* __restrict__ vn_feat, const float* __restrict__ vn_pos,
    const float* __restrict__ agg_feat, const float* __restrict__ agg_vr,
    const float* __restrict__ agg_rv, const float* __restrict__ cnt,
    const float* __restrict__ ftw1, const float* __restrict__ ftb1,
    const float* __restrict__ ftw2, const float* __restrict__ ftb2,
    const float* __restrict__ f2tw1, const float* __restrict__ f2tb1,
    const float* __restrict__ f2tw2, const float* __restrict__ f2tb2,
    const float* __restrict__ vfw1, const float* __restrict__ vfb1,
    const float* __restrict__ vfw2, const float* __restrict__ vfb2,
    float* __restrict__ out, int Nn)
{
    __shared__ float At[16][260];
    __shared__ float Ht[16][260];
    __shared__ float Wt[16][256];
    __shared__ float rc[16];
    const int t  = threadIdx.x;
    const int n0 = blockIdx.x * 16;
    float* nf_out = out;
    float* np_out = out + (size_t)Nn * FEAT;
    float* vf_out = np_out + (size_t)Nn * 3;
    float* vp_out = vf_out + (size_t)Nn * HDIM;

    if (t < 16) rc[t] = 1.0f / fmaxf(cnt[n0 + t], 1.0f);
    __syncthreads();
    #pragma unroll
    for (int i = 0; i < 4; ++i) {
        const int p = t + i * 256;
        const int r = p >> 6, cc = (p & 63) * 4;
        float4 v = *(const float4*)&agg_feat[(size_t)(n0 + r) * HDIM + cc];
        const float s = rc[r];
        v.x *= s; v.y *= s; v.z *= s; v.w *= s;
        *(float4*)&At[r][cc] = v;
    }
    __syncthreads();
    const int c4 = (t & 63) * 4;
    const int rg = t >> 6;
    float acc[4][4];

    // ---- vf MLP ----
    gemm16x256(At, Wt, vfw1, acc, t, c4, rg);
    {
        const float4 bb = *(const float4*)&vfb1[c4];
        #pragma unroll
        for (int j = 0; j < 4; ++j) {
            float4 h;
            h.x = silu_f(acc[j][0] + bb.x); h.y = silu_f(acc[j][1] + bb.y);
            h.z = silu_f(acc[j][2] + bb.z); h.w = silu_f(acc[j][3] + bb.w);
            *(float4*)&Ht[rg * 4 + j][c4] = h;
        }
    }
    __syncthreads();
    gemm16x256(Ht, Wt, vfw2, acc, t, c4, rg);
    {
        const float4 bb = *(const float4*)&vfb2[c4];
        #pragma unroll
        for (int j = 0; j < 4; ++j) {
            const int r = rg * 4 + j;
            float4 v = *(const float4*)&vn_feat[(size_t)(n0 + r) * HDIM + c4];
            v.x += acc[j][0] + bb.x; v.y += acc[j][1] + bb.y;
            v.z += acc[j][2] + bb.z; v.w += acc[j][3] + bb.w;
            *(float4*)&vf_out[(size_t)(n0 + r) * HDIM + c4] = v;
        }
    }

    // ---- ft MLP ----
    gemm16x256(At, Wt, ftw1, acc, t, c4, rg);
    {
        const float4 bb = *(const float4*)&ftb1[c4];
        #pragma unroll
        for (int j = 0; j < 4; ++j) {
            float4 h;
            h.x = silu_f(acc[j][0] + bb.x); h.y = silu_f(acc[j][1] + bb.y);
            h.z = silu_f(acc[j][2] + bb.z); h.w = silu_f(acc[j][3] + bb.w);
            *(float4*)&Ht[rg * 4 + j][c4] = h;
        }
    }
    __syncthreads();
    gemm16x256(Ht, Wt, ftw2, acc, t, c4, rg);
    {
        const float4 bb = *(const float4*)&ftb2[c4];
        #pragma unroll
        for (int j = 0; j < 4; ++j) {
            float4 v;
            v.x = acc[j][0] + bb.x; v.y = acc[j][1] + bb.y;
            v.z = acc[j][2] + bb.z; v.w = acc[j][3] + bb.w;
            *(float4*)&At[rg * 4 + j][c4] = v;
        }
    }
    __syncthreads();

    // ---- f2t MLP ----
    gemm16x256(At, Wt, f2tw1, acc, t, c4, rg);
    {
        const float4 bb = *(const float4*)&f2tb1[c4];
        #pragma unroll
        for (int j = 0; j < 4; ++j) {
            float4 h;
            h.x = silu_f(acc[j][0] + bb.x); h.y = silu_f(acc[j][1] + bb.y);
            h.z = silu_f(acc[j][2] + bb.z); h.w = silu_f(acc[j][3] + bb.w);
            *(float4*)&Ht[rg * 4 + j][c4] = h;
        }
    }
    __syncthreads();
    {
        const int c4b = (t & 31) * 4;
        const int rgb = t >> 5;
        float* Wfl = &Wt[0][0];
        float a3[2][4] = {};
        for (int k0 = 0; k0 < 256; k0 += 16) {
            #pragma unroll
            for (int i = 0; i < 2; ++i) {
                const int p  = t + i * 256;
                const int wr = p >> 5, wc = (p & 31) * 4;
                *(float4*)&Wfl[wr * 128 + wc] =
                    *(const float4*)&f2tw2[(size_t)(k0 + wr) * SDIM + wc];
            }
            __syncthreads();
            #pragma unroll
            for (int kk = 0; kk < 16; ++kk) {
                const float4 w = *(const float4*)&Wfl[kk * 128 + c4b];
                #pragma unroll
                for (int j = 0; j < 2; ++j) {
                    const float a = Ht[rgb * 2 + j][k0 + kk];
                    a3[j][0] = fmaf(a, w.x, a3[j][0]); a3[j][1] = fmaf(a, w.y, a3[j][1]);
                    a3[j][2] = fmaf(a, w.z, a3[j][2]); a3[j][3] = fmaf(a, w.w, a3[j][3]);
                }
            }
            __syncthreads();
        }
        const float4 bb = *(const float4*)&f2tb2[c4b];
        #pragma unroll
        for (int j = 0; j < 2; ++j) {
            const int r = rgb * 2 + j;
            float4 v = *(const float4*)&node_feat[(size_t)(n0 + r) * FEAT + c4b];
            v.x += a3[j][0] + bb.x; v.y += a3[j][1] + bb.y;
            v.z += a3[j][2] + bb.z; v.w += a3[j][3] + bb.w;
            *(float4*)&nf_out[(size_t)(n0 + r) * FEAT + c4b] = v;
        }
    }

    for (int p = t; p < 16 * 352; p += 256) {
        const int r  = p / 352;
        const int cc = 128 + (p % 352);
        nf_out[(size_t)(n0 + r) * FEAT + cc] = node_feat[(size_t)(n0 + r) * FEAT + cc];
    }
    if (t < 16) {
        const int n = n0 + t;
        const float s = rc[t];
        #pragma unroll
        for (int j = 0; j < 3; ++j)
            np_out[(size_t)n * 3 + j] = node_pos[(size_t)n * 3 + j] + agg_vr[(size_t)n * 3 + j] * s;
        #pragma unroll
        for (int j = 0; j < 12; ++j)
            vp_out[(size_t)n * 12 + j] = vn_pos[(size_t)n * 12 + j] + agg_rv[(size_t)n * 12 + j] * s;
    }
}

// ---------------------------------------------------------------- launch
extern "C" void kernel_launch(void* const* d_in, const int* in_sizes, int n_in,
                              void* d_out, int out_size, void* d_ws, size_t ws_size,
                              hipStream_t stream)
{
    (void)n_in; (void)out_size; (void)ws_size;
    const float* node_feat = (const float*)d_in[0];
    const float* node_pos  = (const float*)d_in[1];
    const float* vn_feat   = (const float*)d_in[2];
    const float* vn_pos    = (const float*)d_in[3];
    const int*   eidx      = (const int*)d_in[4];
    const float* w_scalar  = (const float*)d_in[5];
    const float* cm_w1  = (const float*)d_in[6];
    const float* cm_b1  = (const float*)d_in[7];
    const float* cm_w2  = (const float*)d_in[8];
    const float* cm_b2  = (const float*)d_in[9];
    const float* vr_w1  = (const float*)d_in[10];
    const float* vr_b1  = (const float*)d_in[11];
    const float* vr_w2  = (const float*)d_in[12];
    const float* vr_b2  = (const float*)d_in[13];
    const float* rv_w1  = (const float*)d_in[14];
    const float* rv_b1  = (const float*)d_in[15];
    const float* rv_w2  = (const float*)d_in[16];
    const float* rv_b2  = (const float*)d_in[17];
    const float* ft_w1  = (const float*)d_in[18];
    const float* ft_b1  = (const float*)d_in[19];
    const float* ft_w2  = (const float*)d_in[20];
    const float* ft_b2  = (const float*)d_in[21];
    const float* f2t_w1 = (const float*)d_in[22];
    const float* f2t_b1 = (const float*)d_in[23];
    const float* f2t_w2 = (const float*)d_in[24];
    const float* f2t_b2 = (const float*)d_in[25];
    const float* vf_w1  = (const float*)d_in[26];
    const float* vf_b1  = (const float*)d_in[27];
    const float* vf_w2  = (const float*)d_in[28];
    const float* vf_b2  = (const float*)d_in[29];

    const int Nn = in_sizes[0] / FEAT;        // 20000
    const int E  = in_sizes[4] / 2;           // 240000

    float* ws       = (float*)d_ws;
    float* agg_feat = ws;                                // Nn*256
    float* agg_vr   = agg_feat + (size_t)Nn * HDIM;      // Nn*3
    float* agg_rv   = agg_vr   + (size_t)Nn * 3;         // Nn*12
    float* cnt      = agg_rv   + (size_t)Nn * 12;        // Nn
    ushort* nfsb  = (ushort*)(cnt + Nn);                 // Nn*128
    ushort* vnb   = nfsb  + (size_t)Nn * SDIM;           // Nn*256
    ushort* w1t   = vnb   + (size_t)Nn * HDIM;           // 256*416
    ushort* w2t   = w1t   + 256 * 416;
    ushort* vrw1t = w2t   + 256 * 256;
    ushort* rvw1t = vrw1t + 256 * 256;
    ushort* vrw2t = rvw1t + 256 * 256;
    ushort* rvw2t = vrw2t + 16 * 256;

    const size_t zero_bytes = (size_t)Nn * (HDIM + 3 + 12 + 1) * sizeof(float);
    hipMemsetAsync(agg_feat, 0, zero_bytes, stream);

    k_wprep<<<1216, 256, 0, stream>>>(cm_w1, cm_w2, vr_w1, rv_w1, vr_w2, rv_w2,
                                      w1t, w2t, vrw1t, rvw1t, vrw2t, rvw2t);
    k_vnb<<<(Nn * 64 + 255) / 256, 256, 0, stream>>>(vn_feat, vnb, Nn * 64);
    k_nfs<<<Nn / 32, 256, 0, stream>>>(node_feat, w_scalar, nfsb);
    k_edge<<<E / 32, 256, 0, stream>>>(nfsb, vnb, node_pos, vn_pos, eidx,
                                       w1t, cm_b1, w2t, cm_b2,
                                       vrw1t, vr_b1, vrw2t, vr_b2,
                                       rvw1t, rv_b1, rvw2t, rv_b2,
                                       agg_feat, agg_vr, agg_rv, cnt, E);
    k_node<<<Nn / 16, 256, 0, stream>>>(node_feat, node_pos, vn_feat, vn_pos,
                                        agg_feat, agg_vr, agg_rv, cnt,
                                        ft_w1, ft_b1, ft_w2, ft_b2,
                                        f2t_w1, f2t_b1, f2t_w2, f2t_b2,
                                        vf_w1, vf_b1, vf_w2, vf_b2,
                                        (float*)d_out, Nn);
}

// Round 5
// 908.927 us; speedup vs baseline: 3.5434x; 1.1232x over previous
//
#include <hip/hip_runtime.h>
#include <hip/hip_bf16.h>
#include <math.h>

// VNLayer: N=20000 nodes, E=240000 edges, H=256, SD=128, C=4, FEAT=480
// Round 5: kill the atomic storm. CSR counting-sort of edges by row, then
// k_edge consumes row-sorted edges and does in-block SEGMENTED reduction of
// msg / vr / rv (one coalesced atomic per row-segment instead of per edge).
// agg_feat atomics: 61.4M -> ~9.6M.

#define FEAT 480
#define HDIM 256
#define SDIM 128
#define MSTR 264    // msg/hidden LDS row stride (ushorts)

typedef __attribute__((ext_vector_type(8))) short bf16x8;
typedef __attribute__((ext_vector_type(4))) float f32x4;

__device__ __forceinline__ float silu_f(float x) {
    return x / (1.0f + __expf(-x));
}
__device__ __forceinline__ ushort f2b(float v) {
    __hip_bfloat16 h = __float2bfloat16(v);
    return *(ushort*)&h;
}
__device__ __forceinline__ float b2f(ushort u) {
    union { unsigned int i; float f; } c;
    c.i = ((unsigned int)u) << 16;
    return c.f;
}

// ---------------------------------------------------------------- CSR build
__global__ __launch_bounds__(256) void k_count(
    const int* __restrict__ eidx, int* __restrict__ cnt_i, int E)
{
    const int e = blockIdx.x * 256 + threadIdx.x;
    if (e < E) atomicAdd(&cnt_i[eidx[e]], 1);
}

__global__ __launch_bounds__(1024) void k_scan(
    const int* __restrict__ cnt_i, int* __restrict__ rowstart,
    float* __restrict__ cntf, int Nn)
{
    __shared__ int sh[1024];
    __shared__ int carry_s;
    const int t = threadIdx.x;
    if (t == 0) carry_s = 0;
    __syncthreads();
    const int nch = (Nn + 1023) / 1024;
    for (int ch = 0; ch < nch; ++ch) {
        const int i = ch * 1024 + t;
        const int v = (i < Nn) ? cnt_i[i] : 0;
        sh[t] = v;
        __syncthreads();
        for (int off = 1; off < 1024; off <<= 1) {
            const int add = (t >= off) ? sh[t - off] : 0;
            __syncthreads();
            sh[t] += add;
            __syncthreads();
        }
        const int incl = sh[t];
        const int carry = carry_s;
        if (i < Nn) {
            rowstart[i + 1] = carry + incl;
            cntf[i] = fmaxf((float)v, 1.0f);
        }
        __syncthreads();
        if (t == 1023) carry_s = carry + incl;
        __syncthreads();
    }
    if (t == 0) rowstart[0] = 0;
}

__global__ __launch_bounds__(256) void k_place(
    const int* __restrict__ eidx, const int* __restrict__ rowstart,
    int* __restrict__ cursor, int* __restrict__ elist, int E)
{
    const int e = blockIdx.x * 256 + threadIdx.x;
    if (e < E) {
        const int r = eidx[e];
        const int p = atomicAdd(&cursor[r], 1);
        elist[rowstart[r] + p] = e;
    }
}

// ---------------------------------------------------------------- k_wprep
__global__ __launch_bounds__(256) void k_wprep(
    const float* __restrict__ w1, const float* __restrict__ w2,
    const float* __restrict__ vrw1, const float* __restrict__ rvw1,
    const float* __restrict__ vrw2, const float* __restrict__ rvw2,
    ushort* __restrict__ w1t, ushort* __restrict__ w2t,
    ushort* __restrict__ vrw1t, ushort* __restrict__ rvw1t,
    ushort* __restrict__ vrw2t, ushort* __restrict__ rvw2t)
{
    const int idx = blockIdx.x * 256 + threadIdx.x;
    const int S1 = 256 * 416, S2 = 256 * 256;
    if (idx < S1) {
        const int n = idx / 416, k = idx % 416;
        w1t[idx] = (k < 400) ? f2b(w1[(size_t)k * 256 + n]) : (ushort)0;
    } else if (idx < S1 + S2) {
        const int o = idx - S1, n = o >> 8, k = o & 255;
        w2t[o] = f2b(w2[(size_t)k * 256 + n]);
    } else if (idx < S1 + 2 * S2) {
        const int o = idx - S1 - S2, n = o >> 8, k = o & 255;
        vrw1t[o] = f2b(vrw1[(size_t)k * 256 + n]);
    } else if (idx < S1 + 3 * S2) {
        const int o = idx - S1 - 2 * S2, n = o >> 8, k = o & 255;
        rvw1t[o] = f2b(rvw1[(size_t)k * 256 + n]);
    } else if (idx < S1 + 3 * S2 + 4096) {
        const int o = idx - S1 - 3 * S2, c = o >> 8, k = o & 255;
        vrw2t[o] = (c < 4) ? f2b(vrw2[(size_t)k * 4 + c]) : (ushort)0;
    } else if (idx < S1 + 3 * S2 + 8192) {
        const int o = idx - S1 - 3 * S2 - 4096, c = o >> 8, k = o & 255;
        rvw2t[o] = f2b(rvw2[(size_t)k * 16 + c]);
    }
}

// ---------------------------------------------------------------- k_vnb
__global__ __launch_bounds__(256) void k_vnb(
    const float* __restrict__ vn_feat, ushort* __restrict__ vnb, int total4)
{
    const int i = blockIdx.x * 256 + threadIdx.x;
    if (i >= total4) return;
    const float4 v = *(const float4*)&vn_feat[(size_t)i * 4];
    ushort4 o;
    o.x = f2b(v.x); o.y = f2b(v.y); o.z = f2b(v.z); o.w = f2b(v.w);
    *(ushort4*)&vnb[(size_t)i * 4] = o;
}

// ---------------------------------------------------------------- k_nfs
__global__ __launch_bounds__(256) void k_nfs(
    const float* __restrict__ node_feat, const float* __restrict__ w_scalar,
    ushort* __restrict__ nfsb)
{
    __shared__ float At[32][20];
    __shared__ float Wt[16][128];
    const int t  = threadIdx.x;
    const int m0 = blockIdx.x * 32;
    const int c4 = (t & 31) * 4;
    const int rg = t >> 5;
    float acc[4][4] = {};
    for (int k0 = 0; k0 < 128; k0 += 16) {
        if (t < 128) {
            const int r = t >> 2, kk = (t & 3) * 4;
            *(float4*)&At[r][kk] =
                *(const float4*)&node_feat[(size_t)(m0 + r) * FEAT + k0 + kk];
        }
        #pragma unroll
        for (int i = 0; i < 2; ++i) {
            const int p  = t + i * 256;
            const int wr = p >> 5, wc = (p & 31) * 4;
            *(float4*)&Wt[wr][wc] =
                *(const float4*)&w_scalar[(size_t)(k0 + wr) * SDIM + wc];
        }
        __syncthreads();
        #pragma unroll
        for (int kk = 0; kk < 16; ++kk) {
            const float4 w = *(const float4*)&Wt[kk][c4];
            #pragma unroll
            for (int j = 0; j < 4; ++j) {
                const float a = At[rg * 4 + j][kk];
                acc[j][0] = fmaf(a, w.x, acc[j][0]);
                acc[j][1] = fmaf(a, w.y, acc[j][1]);
                acc[j][2] = fmaf(a, w.z, acc[j][2]);
                acc[j][3] = fmaf(a, w.w, acc[j][3]);
            }
        }
        __syncthreads();
    }
    const float s = 0.08838834764831845f;
    #pragma unroll
    for (int j = 0; j < 4; ++j) {
        ushort4 o;
        o.x = f2b(acc[j][0] * s); o.y = f2b(acc[j][1] * s);
        o.z = f2b(acc[j][2] * s); o.w = f2b(acc[j][3] * s);
        *(ushort4*)&nfsb[(size_t)(m0 + rg * 4 + j) * SDIM + c4] = o;
    }
}

// ---------------------------------------------------------------- k_edge
// 32 row-sorted edges/block, 256 threads = 4 waves. LDS 39.2KB -> 4 blk/CU.
__global__ __launch_bounds__(256, 4) void k_edge(
    const ushort* __restrict__ nfsb, const ushort* __restrict__ vnb,
    const float* __restrict__ node_pos, const float* __restrict__ vn_pos,
    const int* __restrict__ eidx, const int* __restrict__ elist,
    const ushort* __restrict__ w1t, const float* __restrict__ b1,
    const ushort* __restrict__ w2t, const float* __restrict__ b2,
    const ushort* __restrict__ vrw1t, const float* __restrict__ vrb1,
    const ushort* __restrict__ vrw2t, const float* __restrict__ vrb2,
    const ushort* __restrict__ rvw1t, const float* __restrict__ rvb1,
    const ushort* __restrict__ rvw2t, const float* __restrict__ rvb2,
    float* __restrict__ agg_feat, float* __restrict__ agg_vr,
    float* __restrict__ agg_rv, int E)
{
    __shared__ ushort Mg[32 * MSTR];   // 16.9 KB msg (bf16)
    __shared__ ushort Hd[32 * MSTR];   // 16.9 KB hidden
    __shared__ ushort ipB[32 * 16];    // 1 KB gram bf16
    __shared__ float dnS[32][12];
    __shared__ float wvrS[32][4];
    __shared__ float wrvS[32][16];     // later overlaid with ev[15] per edge
    __shared__ int rowi[32], coli[32];

    const int t  = threadIdx.x;
    const int e0 = blockIdx.x * 32;
    const int wv = t >> 6;
    const int lane = t & 63;
    const int lr = lane & 15;
    const int lk = lane >> 4;
    const int colBase = wv * 64;

    // ---- geometry (t<32), edges in row-sorted order ----
    if (t < 32) {
        const int e = elist[e0 + t];
        const int r = eidx[e];
        const int c = eidx[E + e];
        rowi[t] = r; coli[t] = c;
        const float px = node_pos[r * 3 + 0];
        const float py = node_pos[r * 3 + 1];
        const float pz = node_pos[r * 3 + 2];
        float d[4][3];
        #pragma unroll
        for (int ch = 0; ch < 4; ++ch) {
            d[ch][0] = px - vn_pos[(size_t)c * 12 + ch * 3 + 0];
            d[ch][1] = py - vn_pos[(size_t)c * 12 + ch * 3 + 1];
            d[ch][2] = pz - vn_pos[(size_t)c * 12 + ch * 3 + 2];
        }
        float ss = 0.f, ipv[16];
        #pragma unroll
        for (int ci = 0; ci < 4; ++ci)
            #pragma unroll
            for (int ck = 0; ck < 4; ++ck) {
                const float v = d[ci][0]*d[ck][0] + d[ci][1]*d[ck][1] + d[ci][2]*d[ck][2];
                ipv[ci * 4 + ck] = v; ss += v * v;
            }
        const float inrm = 1.0f / fmaxf(sqrtf(ss), 1e-8f);
        #pragma unroll
        for (int i = 0; i < 16; ++i) ipB[t * 16 + i] = f2b(ipv[i] * inrm);
        #pragma unroll
        for (int ch = 0; ch < 4; ++ch) {
            const float nn = sqrtf(d[ch][0]*d[ch][0] + d[ch][1]*d[ch][1] + d[ch][2]*d[ch][2]);
            const float s = 1.0f / fmaxf(nn, 1e-8f);
            dnS[t][ch * 3 + 0] = d[ch][0] * s;
            dnS[t][ch * 3 + 1] = d[ch][1] * s;
            dnS[t][ch * 3 + 2] = d[ch][2] * s;
        }
    }
    __syncthreads();

    // per-lane A row bases for cm1 direct-global reads
    const ushort* nA0 = nfsb + (size_t)rowi[lr]      * SDIM + lk * 8;
    const ushort* nA1 = nfsb + (size_t)rowi[lr + 16] * SDIM + lk * 8;
    const ushort* vA0 = vnb  + (size_t)coli[lr]      * HDIM + lk * 8;
    const ushort* vA1 = vnb  + (size_t)coli[lr + 16] * HDIM + lk * 8;

    f32x4 acc[2][4];
    #pragma unroll
    for (int mt = 0; mt < 2; ++mt)
        #pragma unroll
        for (int nt = 0; nt < 4; ++nt) acc[mt][nt] = (f32x4)0.f;

    // ===== cm layer 1 (K=416: 128 nfs | 256 vn | 16 ip | 16 zero) =====
    #pragma unroll
    for (int ks = 0; ks < 13; ++ks) {
        bf16x8 a0, a1;
        if (ks < 4) {
            a0 = *(const bf16x8*)(nA0 + ks * 32);
            a1 = *(const bf16x8*)(nA1 + ks * 32);
        } else if (ks < 12) {
            a0 = *(const bf16x8*)(vA0 + ks * 32 - 128);
            a1 = *(const bf16x8*)(vA1 + ks * 32 - 128);
        } else if (lk < 2) {
            a0 = *(const bf16x8*)&ipB[lr * 16 + lk * 8];
            a1 = *(const bf16x8*)&ipB[(lr + 16) * 16 + lk * 8];
        } else {
            a0 = (bf16x8)(short)0;
            a1 = (bf16x8)(short)0;
        }
        #pragma unroll
        for (int nt = 0; nt < 4; ++nt) {
            const bf16x8 b = *(const bf16x8*)&w1t[(size_t)(colBase + nt * 16 + lr) * 416 + ks * 32 + lk * 8];
            acc[0][nt] = __builtin_amdgcn_mfma_f32_16x16x32_bf16(a0, b, acc[0][nt], 0, 0, 0);
            acc[1][nt] = __builtin_amdgcn_mfma_f32_16x16x32_bf16(a1, b, acc[1][nt], 0, 0, 0);
        }
    }
    #pragma unroll
    for (int nt = 0; nt < 4; ++nt) {
        const int col = colBase + nt * 16 + lr;
        const float bb = b1[col];
        #pragma unroll
        for (int mt = 0; mt < 2; ++mt)
            #pragma unroll
            for (int r = 0; r < 4; ++r) {
                const int row = mt * 16 + lk * 4 + r;
                Hd[row * MSTR + col] = f2b(silu_f(acc[mt][nt][r] + bb));
            }
    }
    __syncthreads();

#define KLOOP_LDS(SRC, WBASE)                                                  \
    {                                                                          \
        _Pragma("unroll")                                                      \
        for (int mt = 0; mt < 2; ++mt)                                         \
            _Pragma("unroll")                                                  \
            for (int nt = 0; nt < 4; ++nt) acc[mt][nt] = (f32x4)0.f;           \
        _Pragma("unroll")                                                      \
        for (int ks = 0; ks < 8; ++ks) {                                       \
            const bf16x8 a0 = *(const bf16x8*)&(SRC)[lr * MSTR + ks * 32 + lk * 8];        \
            const bf16x8 a1 = *(const bf16x8*)&(SRC)[(lr + 16) * MSTR + ks * 32 + lk * 8]; \
            _Pragma("unroll")                                                  \
            for (int nt = 0; nt < 4; ++nt) {                                   \
                const bf16x8 b = *(const bf16x8*)&(WBASE)[(size_t)(colBase + nt * 16 + lr) * 256 + ks * 32 + lk * 8]; \
                acc[0][nt] = __builtin_amdgcn_mfma_f32_16x16x32_bf16(a0, b, acc[0][nt], 0, 0, 0); \
                acc[1][nt] = __builtin_amdgcn_mfma_f32_16x16x32_bf16(a1, b, acc[1][nt], 0, 0, 0); \
            }                                                                  \
        }                                                                      \
    }

    // ===== cm layer 2 -> msg (Mg), no atomics =====
    KLOOP_LDS(Hd, w2t);
    #pragma unroll
    for (int nt = 0; nt < 4; ++nt) {
        const int col = colBase + nt * 16 + lr;
        const float bb = b2[col];
        #pragma unroll
        for (int mt = 0; mt < 2; ++mt)
            #pragma unroll
            for (int r = 0; r < 4; ++r) {
                const int row = mt * 16 + lk * 4 + r;
                Mg[row * MSTR + col] = f2b(acc[mt][nt][r] + bb);
            }
    }
    __syncthreads();

    // ===== segmented reduction of msg -> agg_feat (thread t = column t) =====
    {
        float s = 0.f;
        int prev = rowi[0];
        for (int r = 0; r < 32; ++r) {
            const int rr = rowi[r];                 // uniform broadcast
            if (rr != prev) {                       // uniform branch
                atomicAdd(&agg_feat[(size_t)prev * HDIM + t], s);
                s = 0.f; prev = rr;
            }
            s += b2f(Mg[r * MSTR + t]);
        }
        atomicAdd(&agg_feat[(size_t)prev * HDIM + t], s);
    }

    // ===== vr layer 1 =====
    KLOOP_LDS(Mg, vrw1t);
    #pragma unroll
    for (int nt = 0; nt < 4; ++nt) {
        const int col = colBase + nt * 16 + lr;
        const float bb = vrb1[col];
        #pragma unroll
        for (int mt = 0; mt < 2; ++mt)
            #pragma unroll
            for (int r = 0; r < 4; ++r) {
                const int row = mt * 16 + lk * 4 + r;
                Hd[row * MSTR + col] = f2b(silu_f(acc[mt][nt][r] + bb));
            }
    }
    __syncthreads();

    // ===== vr layer 2 (wave 0, N=4 padded to 16) =====
    if (wv == 0) {
        f32x4 a2[2]; a2[0] = (f32x4)0.f; a2[1] = (f32x4)0.f;
        #pragma unroll
        for (int ks = 0; ks < 8; ++ks) {
            const bf16x8 a0 = *(const bf16x8*)&Hd[lr * MSTR + ks * 32 + lk * 8];
            const bf16x8 a1 = *(const bf16x8*)&Hd[(lr + 16) * MSTR + ks * 32 + lk * 8];
            const bf16x8 b  = *(const bf16x8*)&vrw2t[(size_t)lr * 256 + ks * 32 + lk * 8];
            a2[0] = __builtin_amdgcn_mfma_f32_16x16x32_bf16(a0, b, a2[0], 0, 0, 0);
            a2[1] = __builtin_amdgcn_mfma_f32_16x16x32_bf16(a1, b, a2[1], 0, 0, 0);
        }
        if (lr < 4) {
            const float bb = vrb2[lr];
            #pragma unroll
            for (int mt = 0; mt < 2; ++mt)
                #pragma unroll
                for (int r = 0; r < 4; ++r)
                    wvrS[mt * 16 + lk * 4 + r][lr] = a2[mt][r] + bb;
        }
    }
    __syncthreads();

    // ===== rv layer 1 =====
    KLOOP_LDS(Mg, rvw1t);
    #pragma unroll
    for (int nt = 0; nt < 4; ++nt) {
        const int col = colBase + nt * 16 + lr;
        const float bb = rvb1[col];
        #pragma unroll
        for (int mt = 0; mt < 2; ++mt)
            #pragma unroll
            for (int r = 0; r < 4; ++r) {
                const int row = mt * 16 + lk * 4 + r;
                Hd[row * MSTR + col] = f2b(silu_f(acc[mt][nt][r] + bb));
            }
    }
    __syncthreads();

    // ===== rv layer 2 (wave 0, N=16) =====
    if (wv == 0) {
        f32x4 a2[2]; a2[0] = (f32x4)0.f; a2[1] = (f32x4)0.f;
        #pragma unroll
        for (int ks = 0; ks < 8; ++ks) {
            const bf16x8 a0 = *(const bf16x8*)&Hd[lr * MSTR + ks * 32 + lk * 8];
            const bf16x8 a1 = *(const bf16x8*)&Hd[(lr + 16) * MSTR + ks * 32 + lk * 8];
            const bf16x8 b  = *(const bf16x8*)&rvw2t[(size_t)lr * 256 + ks * 32 + lk * 8];
            a2[0] = __builtin_amdgcn_mfma_f32_16x16x32_bf16(a0, b, a2[0], 0, 0, 0);
            a2[1] = __builtin_amdgcn_mfma_f32_16x16x32_bf16(a1, b, a2[1], 0, 0, 0);
        }
        const float bb = rvb2[lr];
        #pragma unroll
        for (int mt = 0; mt < 2; ++mt)
            #pragma unroll
            for (int r = 0; r < 4; ++r)
                wrvS[mt * 16 + lk * 4 + r][lr] = a2[mt][r] + bb;
    }
    __syncthreads();

    // ===== per-edge geometric update into LDS (t<32, row-local overlay) =====
    if (t < 32) {
        float wvv[4], wrr[16], dn[12], ev[15];
        #pragma unroll
        for (int c = 0; c < 4; ++c)  wvv[c] = wvrS[t][c];
        #pragma unroll
        for (int i = 0; i < 16; ++i) wrr[i] = wrvS[t][i];
        #pragma unroll
        for (int i = 0; i < 12; ++i) dn[i]  = dnS[t][i];
        #pragma unroll
        for (int j = 0; j < 3; ++j) {
            float v = 0.f;
            #pragma unroll
            for (int c = 0; c < 4; ++c) v = fmaf(wvv[c], dn[c * 3 + j], v);
            ev[j] = 0.5f * v;                       // inv = 1/sqrt(4)
        }
        #pragma unroll
        for (int u = 0; u < 4; ++u)
            #pragma unroll
            for (int j = 0; j < 3; ++j) {
                float v = 0.f;
                #pragma unroll
                for (int c = 0; c < 4; ++c) v = fmaf(wrr[c * 4 + u], dn[c * 3 + j], v);
                ev[3 + u * 3 + j] = -0.5f * v;
            }
        #pragma unroll
        for (int i = 0; i < 15; ++i) wrvS[t][i] = ev[i];   // overlay (own row)
    }
    __syncthreads();

    // ===== segmented reduction of vr/rv (t<15: component t) =====
    if (t < 15) {
        float s = 0.f;
        int prev = rowi[0];
        for (int r = 0; r < 32; ++r) {
            const int rr = rowi[r];
            if (rr != prev) {
                if (t < 3) atomicAdd(&agg_vr[(size_t)prev * 3 + t], s);
                else       atomicAdd(&agg_rv[(size_t)prev * 12 + (t - 3)], s);
                s = 0.f; prev = rr;
            }
            s += wrvS[r][t];
        }
        if (t < 3) atomicAdd(&agg_vr[(size_t)prev * 3 + t], s);
        else       atomicAdd(&agg_rv[(size_t)prev * 12 + (t - 3)], s);
    }
#undef KLOOP_LDS
}

// ---------------------------------------------------------------- k_node helpers
__device__ __forceinline__ void gemm16x256(
    const float Ab[16][260], float Wt[16][256], const float* __restrict__ Wsrc,
    float acc[4][4], const int t, const int c4, const int rg)
{
    #pragma unroll
    for (int j = 0; j < 4; ++j) { acc[j][0]=0.f; acc[j][1]=0.f; acc[j][2]=0.f; acc[j][3]=0.f; }
    for (int k0 = 0; k0 < 256; k0 += 16) {
        #pragma unroll
        for (int i = 0; i < 4; ++i) {
            const int p  = t + i * 256;
            const int wr = p >> 6, wc = (p & 63) * 4;
            *(float4*)&Wt[wr][wc] = *(const float4*)&Wsrc[(size_t)(k0 + wr) * 256 + wc];
        }
        __syncthreads();
        #pragma unroll
        for (int kk = 0; kk < 16; ++kk) {
            const float4 w = *(const float4*)&Wt[kk][c4];
            #pragma unroll
            for (int j = 0; j < 4; ++j) {
                const float a = Ab[rg * 4 + j][k0 + kk];
                acc[j][0] = fmaf(a, w.x, acc[j][0]); acc[j][1] = fmaf(a, w.y, acc[j][1]);
                acc[j][2] = fmaf(a, w.z, acc[j][2]); acc[j][3] = fmaf(a, w.w, acc[j][3]);
            }
        }
        __syncthreads();
    }
}

// ---------------------------------------------------------------- k_node
__global__ __launch_bounds__(256) void k_node(
    const float* __restrict__ node_feat, const float* __restrict__ node_pos,
    const float* __restrict__ vn_feat, const float* __restrict__ vn_pos,
    const float* __restrict__ agg_feat, const float* __restrict__ agg_vr,
    const float* __restrict__ agg_rv, const float* __restrict__ cntf,
    const float* __restrict__ ftw1, const float* __restrict__ ftb1,
    const float* __restrict__ ftw2, const float* __restrict__ ftb2,
    const float* __restrict__ f2tw1, const float* __restrict__ f2tb1,
    const float* __restrict__ f2tw2, const float* __restrict__ f2tb2,
    const float* __restrict__ vfw1, const float* __restrict__ vfb1,
    const float* __restrict__ vfw2, const float* __restrict__ vfb2,
    float* __restrict__ out, int Nn)
{
    __shared__ float At[16][260];
    __shared__ float Ht[16][260];
    __shared__ float Wt[16][256];
    __shared__ float rc[16];
    const int t  = threadIdx.x;
    const int n0 = blockIdx.x * 16;
    float* nf_out = out;
    float* np_out = out + (size_t)Nn * FEAT;
    float* vf_out = np_out + (size_t)Nn * 3;
    float* vp_out = vf_out + (size_t)Nn * HDIM;

    if (t < 16) rc[t] = 1.0f / fmaxf(cntf[n0 + t], 1.0f);
    __syncthreads();
    #pragma unroll
    for (int i = 0; i < 4; ++i) {
        const int p = t + i * 256;
        const int r = p >> 6, cc = (p & 63) * 4;
        float4 v = *(const float4*)&agg_feat[(size_t)(n0 + r) * HDIM + cc];
        const float s = rc[r];
        v.x *= s; v.y *= s; v.z *= s; v.w *= s;
        *(float4*)&At[r][cc] = v;
    }
    __syncthreads();
    const int c4 = (t & 63) * 4;
    const int rg = t >> 6;
    float acc[4][4];

    // ---- vf MLP ----
    gemm16x256(At, Wt, vfw1, acc, t, c4, rg);
    {
        const float4 bb = *(const float4*)&vfb1[c4];
        #pragma unroll
        for (int j = 0; j < 4; ++j) {
            float4 h;
            h.x = silu_f(acc[j][0] + bb.x); h.y = silu_f(acc[j][1] + bb.y);
            h.z = silu_f(acc[j][2] + bb.z); h.w = silu_f(acc[j][3] + bb.w);
            *(float4*)&Ht[rg * 4 + j][c4] = h;
        }
    }
    __syncthreads();
    gemm16x256(Ht, Wt, vfw2, acc, t, c4, rg);
    {
        const float4 bb = *(const float4*)&vfb2[c4];
        #pragma unroll
        for (int j = 0; j < 4; ++j) {
            const int r = rg * 4 + j;
            float4 v = *(const float4*)&vn_feat[(size_t)(n0 + r) * HDIM + c4];
            v.x += acc[j][0] + bb.x; v.y += acc[j][1] + bb.y;
            v.z += acc[j][2] + bb.z; v.w += acc[j][3] + bb.w;
            *(float4*)&vf_out[(size_t)(n0 + r) * HDIM + c4] = v;
        }
    }

    // ---- ft MLP ----
    gemm16x256(At, Wt, ftw1, acc, t, c4, rg);
    {
        const float4 bb = *(const float4*)&ftb1[c4];
        #pragma unroll
        for (int j = 0; j < 4; ++j) {
            float4 h;
            h.x = silu_f(acc[j][0] + bb.x); h.y = silu_f(acc[j][1] + bb.y);
            h.z = silu_f(acc[j][2] + bb.z); h.w = silu_f(acc[j][3] + bb.w);
            *(float4*)&Ht[rg * 4 + j][c4] = h;
        }
    }
    __syncthreads();
    gemm16x256(Ht, Wt, ftw2, acc, t, c4, rg);
    {
        const float4 bb = *(const float4*)&ftb2[c4];
        #pragma unroll
        for (int j = 0; j < 4; ++j) {
            float4 v;
            v.x = acc[j][0] + bb.x; v.y = acc[j][1] + bb.y;
            v.z = acc[j][2] + bb.z; v.w = acc[j][3] + bb.w;
            *(float4*)&At[rg * 4 + j][c4] = v;
        }
    }
    __syncthreads();

    // ---- f2t MLP ----
    gemm16x256(At, Wt, f2tw1, acc, t, c4, rg);
    {
        const float4 bb = *(const float4*)&f2tb1[c4];
        #pragma unroll
        for (int j = 0; j < 4; ++j) {
            float4 h;
            h.x = silu_f(acc[j][0] + bb.x); h.y = silu_f(acc[j][1] + bb.y);
            h.z = silu_f(acc[j][2] + bb.z); h.w = silu_f(acc[j][3] + bb.w);
            *(float4*)&Ht[rg * 4 + j][c4] = h;
        }
    }
    __syncthreads();
    {
        const int c4b = (t & 31) * 4;
        const int rgb = t >> 5;
        float* Wfl = &Wt[0][0];
        float a3[2][4] = {};
        for (int k0 = 0; k0 < 256; k0 += 16) {
            #pragma unroll
            for (int i = 0; i < 2; ++i) {
                const int p  = t + i * 256;
                const int wr = p >> 5, wc = (p & 31) * 4;
                *(float4*)&Wfl[wr * 128 + wc] =
                    *(const float4*)&f2tw2[(size_t)(k0 + wr) * SDIM + wc];
            }
            __syncthreads();
            #pragma unroll
            for (int kk = 0; kk < 16; ++kk) {
                const float4 w = *(const float4*)&Wfl[kk * 128 + c4b];
                #pragma unroll
                for (int j = 0; j < 2; ++j) {
                    const float a = Ht[rgb * 2 + j][k0 + kk];
                    a3[j][0] = fmaf(a, w.x, a3[j][0]); a3[j][1] = fmaf(a, w.y, a3[j][1]);
                    a3[j][2] = fmaf(a, w.z, a3[j][2]); a3[j][3] = fmaf(a, w.w, a3[j][3]);
                }
            }
            __syncthreads();
        }
        const float4 bb = *(const float4*)&f2tb2[c4b];
        #pragma unroll
        for (int j = 0; j < 2; ++j) {
            const int r = rgb * 2 + j;
            float4 v = *(const float4*)&node_feat[(size_t)(n0 + r) * FEAT + c4b];
            v.x += a3[j][0] + bb.x; v.y += a3[j][1] + bb.y;
            v.z += a3[j][2] + bb.z; v.w += a3[j][3] + bb.w;
            *(float4*)&nf_out[(size_t)(n0 + r) * FEAT + c4b] = v;
        }
    }

    for (int p = t; p < 16 * 352; p += 256) {
        const int r  = p / 352;
        const int cc = 128 + (p % 352);
        nf_out[(size_t)(n0 + r) * FEAT + cc] = node_feat[(size_t)(n0 + r) * FEAT + cc];
    }
    if (t < 16) {
        const int n = n0 + t;
        const float s = rc[t];
        #pragma unroll
        for (int j = 0; j < 3; ++j)
            np_out[(size_t)n * 3 + j] = node_pos[(size_t)n * 3 + j] + agg_vr[(size_t)n * 3 + j] * s;
        #pragma unroll
        for (int j = 0; j < 12; ++j)
            vp_out[(size_t)n * 12 + j] = vn_pos[(size_t)n * 12 + j] + agg_rv[(size_t)n * 12 + j] * s;
    }
}

// ---------------------------------------------------------------- launch
extern "C" void kernel_launch(void* const* d_in, const int* in_sizes, int n_in,
                              void* d_out, int out_size, void* d_ws, size_t ws_size,
                              hipStream_t stream)
{
    (void)n_in; (void)out_size; (void)ws_size;
    const float* node_feat = (const float*)d_in[0];
    const float* node_pos  = (const float*)d_in[1];
    const float* vn_feat   = (const float*)d_in[2];
    const float* vn_pos    = (const float*)d_in[3];
    const int*   eidx      = (const int*)d_in[4];
    const float* w_scalar  = (const float*)d_in[5];
    const float* cm_w1  = (const float*)d_in[6];
    const float* cm_b1  = (const float*)d_in[7];
    const float* cm_w2  = (const float*)d_in[8];
    const float* cm_b2  = (const float*)d_in[9];
    const float* vr_w1  = (const float*)d_in[10];
    const float* vr_b1  = (const float*)d_in[11];
    const float* vr_w2  = (const float*)d_in[12];
    const float* vr_b2  = (const float*)d_in[13];
    const float* rv_w1  = (const float*)d_in[14];
    const float* rv_b1  = (const float*)d_in[15];
    const float* rv_w2  = (const float*)d_in[16];
    const float* rv_b2  = (const float*)d_in[17];
    const float* ft_w1  = (const float*)d_in[18];
    const float* ft_b1  = (const float*)d_in[19];
    const float* ft_w2  = (const float*)d_in[20];
    const float* ft_b2  = (const float*)d_in[21];
    const float* f2t_w1 = (const float*)d_in[22];
    const float* f2t_b1 = (const float*)d_in[23];
    const float* f2t_w2 = (const float*)d_in[24];
    const float* f2t_b2 = (const float*)d_in[25];
    const float* vf_w1  = (const float*)d_in[26];
    const float* vf_b1  = (const float*)d_in[27];
    const float* vf_w2  = (const float*)d_in[28];
    const float* vf_b2  = (const float*)d_in[29];

    const int Nn = in_sizes[0] / FEAT;        // 20000
    const int E  = in_sizes[4] / 2;           // 240000

    // workspace layout
    float* ws       = (float*)d_ws;
    float* agg_feat = ws;                                // Nn*256  (zeroed)
    float* agg_vr   = agg_feat + (size_t)Nn * HDIM;      // Nn*3    (zeroed)
    float* agg_rv   = agg_vr   + (size_t)Nn * 3;         // Nn*12   (zeroed)
    float* cntf     = agg_rv   + (size_t)Nn * 12;        // Nn      (zeroed)
    int*   cnt_i    = (int*)(cntf + Nn);                 // Nn      (zeroed)
    int*   cursor   = cnt_i + Nn;                        // Nn      (zeroed)
    int*   rowstart = cursor + Nn;                       // Nn+16
    int*   elist    = rowstart + Nn + 16;                // E
    ushort* nfsb  = (ushort*)(elist + E);                // Nn*128
    ushort* vnb   = nfsb  + (size_t)Nn * SDIM;           // Nn*256
    ushort* w1t   = vnb   + (size_t)Nn * HDIM;           // 256*416
    ushort* w2t   = w1t   + 256 * 416;
    ushort* vrw1t = w2t   + 256 * 256;
    ushort* rvw1t = vrw1t + 256 * 256;
    ushort* vrw2t = rvw1t + 256 * 256;
    ushort* rvw2t = vrw2t + 16 * 256;

    const size_t zero_bytes = (size_t)Nn * (HDIM + 3 + 12 + 1 + 2) * sizeof(float);
    hipMemsetAsync(agg_feat, 0, zero_bytes, stream);

    const int eg = (E + 255) / 256;
    k_count<<<eg, 256, 0, stream>>>(eidx, cnt_i, E);
    k_scan<<<1, 1024, 0, stream>>>(cnt_i, rowstart, cntf, Nn);
    k_place<<<eg, 256, 0, stream>>>(eidx, rowstart, cursor, elist, E);
    k_wprep<<<1216, 256, 0, stream>>>(cm_w1, cm_w2, vr_w1, rv_w1, vr_w2, rv_w2,
                                      w1t, w2t, vrw1t, rvw1t, vrw2t, rvw2t);
    k_vnb<<<(Nn * 64 + 255) / 256, 256, 0, stream>>>(vn_feat, vnb, Nn * 64);
    k_nfs<<<Nn / 32, 256, 0, stream>>>(node_feat, w_scalar, nfsb);
    k_edge<<<E / 32, 256, 0, stream>>>(nfsb, vnb, node_pos, vn_pos, eidx, elist,
                                       w1t, cm_b1, w2t, cm_b2,
                                       vrw1t, vr_b1, vrw2t, vr_b2,
                                       rvw1t, rv_b1, rvw2t, rv_b2,
                                       agg_feat, agg_vr, agg_rv, E);
    k_node<<<Nn / 16, 256, 0, stream>>>(node_feat, node_pos, vn_feat, vn_pos,
                                        agg_feat, agg_vr, agg_rv, cntf,
                                        ft_w1, ft_b1, ft_w2, ft_b2,
                                        f2t_w1, f2t_b1, f2t_w2, f2t_b2,
                                        vf_w1, vf_b1, vf_w2, vf_b2,
                                        (float*)d_out, Nn);
}

// Round 6
// 679.616 us; speedup vs baseline: 4.7390x; 1.3374x over previous
//
#include <hip/hip_runtime.h>
#include <hip/hip_bf16.h>
#include <math.h>

// VNLayer: N=20000 nodes, E=240000 edges, H=256, SD=128, C=4, FEAT=480
// Round 6: (1) k_edge K-loops get explicit 1-deep register prefetch
// (software pipeline) to overcome compiler's shallow load scheduling
// (VGPR was 52 -> loads serialized). (2) k_node converted to bf16 MFMA
// (was ~300us of fp32 VALU). CSR + segmented-reduction scatter retained.

#define FEAT 480
#define HDIM 256
#define SDIM 128
#define MSTR 264    // LDS row stride (ushorts)

// bf16 weight arena offsets (ushort elements)
#define OW1   0          // [256][416]
#define OW2   106496     // [256][256]
#define OVR1  172032
#define ORV1  237568
#define OVR2  303104     // [16][256]
#define ORV2  307200     // [16][256]
#define OFT1  311296
#define OFT2  376832
#define OF2T1 442368
#define OF2T2 507904     // [128][256]
#define OVF1  540672
#define OVF2  606208
#define OWTOT 671744

typedef __attribute__((ext_vector_type(8))) short bf16x8;
typedef __attribute__((ext_vector_type(4))) float f32x4;

__device__ __forceinline__ float silu_f(float x) {
    return x / (1.0f + __expf(-x));
}
__device__ __forceinline__ ushort f2b(float v) {
    __hip_bfloat16 h = __float2bfloat16(v);
    return *(ushort*)&h;
}
__device__ __forceinline__ float b2f(ushort u) {
    union { unsigned int i; float f; } c;
    c.i = ((unsigned int)u) << 16;
    return c.f;
}

// K=256 GEMM loop, 2 m-tiles x 4 n-tiles, explicit 1-step register prefetch.
// Uses names: lr, lk, colBase, acc, MSTR.
#define KLOOP_PF(SRC, WBASE)                                                   \
    {                                                                          \
        _Pragma("unroll")                                                      \
        for (int mt = 0; mt < 2; ++mt)                                         \
            _Pragma("unroll")                                                  \
            for (int nt = 0; nt < 4; ++nt) acc[mt][nt] = (f32x4)0.f;           \
        bf16x8 a0c = *(const bf16x8*)&(SRC)[lr * MSTR + lk * 8];               \
        bf16x8 a1c = *(const bf16x8*)&(SRC)[(lr + 16) * MSTR + lk * 8];        \
        bf16x8 b0c = *(const bf16x8*)&(WBASE)[(size_t)(colBase + lr) * 256 + lk * 8];      \
        bf16x8 b1c = *(const bf16x8*)&(WBASE)[(size_t)(colBase + 16 + lr) * 256 + lk * 8]; \
        bf16x8 b2c = *(const bf16x8*)&(WBASE)[(size_t)(colBase + 32 + lr) * 256 + lk * 8]; \
        bf16x8 b3c = *(const bf16x8*)&(WBASE)[(size_t)(colBase + 48 + lr) * 256 + lk * 8]; \
        _Pragma("unroll")                                                      \
        for (int ks = 0; ks < 8; ++ks) {                                       \
            bf16x8 a0n, a1n, b0n, b1n, b2n, b3n;                               \
            if (ks < 7) {                                                      \
                const int k1 = (ks + 1) * 32 + lk * 8;                         \
                a0n = *(const bf16x8*)&(SRC)[lr * MSTR + k1];                  \
                a1n = *(const bf16x8*)&(SRC)[(lr + 16) * MSTR + k1];           \
                b0n = *(const bf16x8*)&(WBASE)[(size_t)(colBase + lr) * 256 + k1];      \
                b1n = *(const bf16x8*)&(WBASE)[(size_t)(colBase + 16 + lr) * 256 + k1]; \
                b2n = *(const bf16x8*)&(WBASE)[(size_t)(colBase + 32 + lr) * 256 + k1]; \
                b3n = *(const bf16x8*)&(WBASE)[(size_t)(colBase + 48 + lr) * 256 + k1]; \
            }                                                                  \
            acc[0][0] = __builtin_amdgcn_mfma_f32_16x16x32_bf16(a0c, b0c, acc[0][0], 0, 0, 0); \
            acc[1][0] = __builtin_amdgcn_mfma_f32_16x16x32_bf16(a1c, b0c, acc[1][0], 0, 0, 0); \
            acc[0][1] = __builtin_amdgcn_mfma_f32_16x16x32_bf16(a0c, b1c, acc[0][1], 0, 0, 0); \
            acc[1][1] = __builtin_amdgcn_mfma_f32_16x16x32_bf16(a1c, b1c, acc[1][1], 0, 0, 0); \
            acc[0][2] = __builtin_amdgcn_mfma_f32_16x16x32_bf16(a0c, b2c, acc[0][2], 0, 0, 0); \
            acc[1][2] = __builtin_amdgcn_mfma_f32_16x16x32_bf16(a1c, b2c, acc[1][2], 0, 0, 0); \
            acc[0][3] = __builtin_amdgcn_mfma_f32_16x16x32_bf16(a0c, b3c, acc[0][3], 0, 0, 0); \
            acc[1][3] = __builtin_amdgcn_mfma_f32_16x16x32_bf16(a1c, b3c, acc[1][3], 0, 0, 0); \
            if (ks < 7) { a0c = a0n; a1c = a1n; b0c = b0n; b1c = b1n; b2c = b2n; b3c = b3n; } \
        }                                                                      \
    }

// silu epilogue into an LDS bf16 matrix
#define EPI_SILU(DST, BIAS)                                                    \
    _Pragma("unroll")                                                          \
    for (int nt = 0; nt < 4; ++nt) {                                           \
        const int col = colBase + nt * 16 + lr;                                \
        const float bb = (BIAS)[col];                                          \
        _Pragma("unroll")                                                      \
        for (int mt = 0; mt < 2; ++mt)                                         \
            _Pragma("unroll")                                                  \
            for (int r = 0; r < 4; ++r) {                                      \
                const int row = mt * 16 + lk * 4 + r;                          \
                (DST)[row * MSTR + col] = f2b(silu_f(acc[mt][nt][r] + bb));    \
            }                                                                  \
    }

// ---------------------------------------------------------------- CSR build
__global__ __launch_bounds__(256) void k_count(
    const int* __restrict__ eidx, int* __restrict__ cnt_i, int E)
{
    const int e = blockIdx.x * 256 + threadIdx.x;
    if (e < E) atomicAdd(&cnt_i[eidx[e]], 1);
}

__global__ __launch_bounds__(1024) void k_scan(
    const int* __restrict__ cnt_i, int* __restrict__ rowstart,
    float* __restrict__ cntf, int Nn)
{
    __shared__ int sh[1024];
    __shared__ int carry_s;
    const int t = threadIdx.x;
    if (t == 0) carry_s = 0;
    __syncthreads();
    const int nch = (Nn + 1023) / 1024;
    for (int ch = 0; ch < nch; ++ch) {
        const int i = ch * 1024 + t;
        const int v = (i < Nn) ? cnt_i[i] : 0;
        sh[t] = v;
        __syncthreads();
        for (int off = 1; off < 1024; off <<= 1) {
            const int add = (t >= off) ? sh[t - off] : 0;
            __syncthreads();
            sh[t] += add;
            __syncthreads();
        }
        const int incl = sh[t];
        const int carry = carry_s;
        if (i < Nn) {
            rowstart[i + 1] = carry + incl;
            cntf[i] = fmaxf((float)v, 1.0f);
        }
        __syncthreads();
        if (t == 1023) carry_s = carry + incl;
        __syncthreads();
    }
    if (t == 0) rowstart[0] = 0;
}

__global__ __launch_bounds__(256) void k_place(
    const int* __restrict__ eidx, const int* __restrict__ rowstart,
    int* __restrict__ cursor, int* __restrict__ elist, int E)
{
    const int e = blockIdx.x * 256 + threadIdx.x;
    if (e < E) {
        const int r = eidx[e];
        const int p = atomicAdd(&cursor[r], 1);
        elist[rowstart[r] + p] = e;
    }
}

// ---------------------------------------------------------------- k_wprep
// All weights -> transposed bf16 [n][k] arena wb.
__global__ __launch_bounds__(256) void k_wprep(
    const float* __restrict__ w1, const float* __restrict__ w2,
    const float* __restrict__ vrw1, const float* __restrict__ rvw1,
    const float* __restrict__ vrw2, const float* __restrict__ rvw2,
    const float* __restrict__ ftw1, const float* __restrict__ ftw2,
    const float* __restrict__ f2tw1, const float* __restrict__ f2tw2,
    const float* __restrict__ vfw1, const float* __restrict__ vfw2,
    ushort* __restrict__ wb)
{
    const int idx = blockIdx.x * 256 + threadIdx.x;
    if (idx >= OWTOT) return;
    ushort v;
    if (idx < OW2) {
        const int n = idx / 416, k = idx % 416;
        v = (k < 400) ? f2b(w1[(size_t)k * 256 + n]) : (ushort)0;
    } else if (idx < OVR1) {
        const int o = idx - OW2;  v = f2b(w2[(size_t)(o & 255) * 256 + (o >> 8)]);
    } else if (idx < ORV1) {
        const int o = idx - OVR1; v = f2b(vrw1[(size_t)(o & 255) * 256 + (o >> 8)]);
    } else if (idx < OVR2) {
        const int o = idx - ORV1; v = f2b(rvw1[(size_t)(o & 255) * 256 + (o >> 8)]);
    } else if (idx < ORV2) {
        const int o = idx - OVR2; const int c = o >> 8, k = o & 255;
        v = (c < 4) ? f2b(vrw2[(size_t)k * 4 + c]) : (ushort)0;
    } else if (idx < OFT1) {
        const int o = idx - ORV2; v = f2b(rvw2[(size_t)(o & 255) * 16 + (o >> 8)]);
    } else if (idx < OFT2) {
        const int o = idx - OFT1; v = f2b(ftw1[(size_t)(o & 255) * 256 + (o >> 8)]);
    } else if (idx < OF2T1) {
        const int o = idx - OFT2; v = f2b(ftw2[(size_t)(o & 255) * 256 + (o >> 8)]);
    } else if (idx < OF2T2) {
        const int o = idx - OF2T1; v = f2b(f2tw1[(size_t)(o & 255) * 256 + (o >> 8)]);
    } else if (idx < OVF1) {
        const int o = idx - OF2T2; v = f2b(f2tw2[(size_t)(o & 255) * 128 + (o >> 8)]);
    } else if (idx < OVF2) {
        const int o = idx - OVF1; v = f2b(vfw1[(size_t)(o & 255) * 256 + (o >> 8)]);
    } else {
        const int o = idx - OVF2; v = f2b(vfw2[(size_t)(o & 255) * 256 + (o >> 8)]);
    }
    wb[idx] = v;
}

// ---------------------------------------------------------------- k_vnb
__global__ __launch_bounds__(256) void k_vnb(
    const float* __restrict__ vn_feat, ushort* __restrict__ vnb, int total4)
{
    const int i = blockIdx.x * 256 + threadIdx.x;
    if (i >= total4) return;
    const float4 v = *(const float4*)&vn_feat[(size_t)i * 4];
    ushort4 o;
    o.x = f2b(v.x); o.y = f2b(v.y); o.z = f2b(v.z); o.w = f2b(v.w);
    *(ushort4*)&vnb[(size_t)i * 4] = o;
}

// ---------------------------------------------------------------- k_nfs
__global__ __launch_bounds__(256) void k_nfs(
    const float* __restrict__ node_feat, const float* __restrict__ w_scalar,
    ushort* __restrict__ nfsb)
{
    __shared__ float At[32][20];
    __shared__ float Wt[16][128];
    const int t  = threadIdx.x;
    const int m0 = blockIdx.x * 32;
    const int c4 = (t & 31) * 4;
    const int rg = t >> 5;
    float acc[4][4] = {};
    for (int k0 = 0; k0 < 128; k0 += 16) {
        if (t < 128) {
            const int r = t >> 2, kk = (t & 3) * 4;
            *(float4*)&At[r][kk] =
                *(const float4*)&node_feat[(size_t)(m0 + r) * FEAT + k0 + kk];
        }
        #pragma unroll
        for (int i = 0; i < 2; ++i) {
            const int p  = t + i * 256;
            const int wr = p >> 5, wc = (p & 31) * 4;
            *(float4*)&Wt[wr][wc] =
                *(const float4*)&w_scalar[(size_t)(k0 + wr) * SDIM + wc];
        }
        __syncthreads();
        #pragma unroll
        for (int kk = 0; kk < 16; ++kk) {
            const float4 w = *(const float4*)&Wt[kk][c4];
            #pragma unroll
            for (int j = 0; j < 4; ++j) {
                const float a = At[rg * 4 + j][kk];
                acc[j][0] = fmaf(a, w.x, acc[j][0]);
                acc[j][1] = fmaf(a, w.y, acc[j][1]);
                acc[j][2] = fmaf(a, w.z, acc[j][2]);
                acc[j][3] = fmaf(a, w.w, acc[j][3]);
            }
        }
        __syncthreads();
    }
    const float s = 0.08838834764831845f;
    #pragma unroll
    for (int j = 0; j < 4; ++j) {
        ushort4 o;
        o.x = f2b(acc[j][0] * s); o.y = f2b(acc[j][1] * s);
        o.z = f2b(acc[j][2] * s); o.w = f2b(acc[j][3] * s);
        *(ushort4*)&nfsb[(size_t)(m0 + rg * 4 + j) * SDIM + c4] = o;
    }
}

// ---------------------------------------------------------------- k_edge
__global__ __launch_bounds__(256, 4) void k_edge(
    const ushort* __restrict__ nfsb, const ushort* __restrict__ vnb,
    const float* __restrict__ node_pos, const float* __restrict__ vn_pos,
    const int* __restrict__ eidx, const int* __restrict__ elist,
    const ushort* __restrict__ wb,
    const float* __restrict__ b1, const float* __restrict__ b2,
    const float* __restrict__ vrb1, const float* __restrict__ vrb2,
    const float* __restrict__ rvb1, const float* __restrict__ rvb2,
    float* __restrict__ agg_feat, float* __restrict__ agg_vr,
    float* __restrict__ agg_rv, int E)
{
    __shared__ ushort Mg[32 * MSTR];
    __shared__ ushort Hd[32 * MSTR];
    __shared__ ushort ipB[32 * 16];
    __shared__ float dnS[32][12];
    __shared__ float wvrS[32][4];
    __shared__ float wrvS[32][16];
    __shared__ int rowi[32], coli[32];

    const int t  = threadIdx.x;
    const int e0 = blockIdx.x * 32;
    const int wv = t >> 6;
    const int lane = t & 63;
    const int lr = lane & 15;
    const int lk = lane >> 4;
    const int colBase = wv * 64;

    const ushort* w1t   = wb + OW1;
    const ushort* w2t   = wb + OW2;
    const ushort* vrw1t = wb + OVR1;
    const ushort* rvw1t = wb + ORV1;
    const ushort* vrw2t = wb + OVR2;
    const ushort* rvw2t = wb + ORV2;

    // ---- geometry (t<32), row-sorted edges ----
    if (t < 32) {
        const int e = elist[e0 + t];
        const int r = eidx[e];
        const int c = eidx[E + e];
        rowi[t] = r; coli[t] = c;
        const float px = node_pos[r * 3 + 0];
        const float py = node_pos[r * 3 + 1];
        const float pz = node_pos[r * 3 + 2];
        float d[4][3];
        #pragma unroll
        for (int ch = 0; ch < 4; ++ch) {
            d[ch][0] = px - vn_pos[(size_t)c * 12 + ch * 3 + 0];
            d[ch][1] = py - vn_pos[(size_t)c * 12 + ch * 3 + 1];
            d[ch][2] = pz - vn_pos[(size_t)c * 12 + ch * 3 + 2];
        }
        float ss = 0.f, ipv[16];
        #pragma unroll
        for (int ci = 0; ci < 4; ++ci)
            #pragma unroll
            for (int ck = 0; ck < 4; ++ck) {
                const float v = d[ci][0]*d[ck][0] + d[ci][1]*d[ck][1] + d[ci][2]*d[ck][2];
                ipv[ci * 4 + ck] = v; ss += v * v;
            }
        const float inrm = 1.0f / fmaxf(sqrtf(ss), 1e-8f);
        #pragma unroll
        for (int i = 0; i < 16; ++i) ipB[t * 16 + i] = f2b(ipv[i] * inrm);
        #pragma unroll
        for (int ch = 0; ch < 4; ++ch) {
            const float nn = sqrtf(d[ch][0]*d[ch][0] + d[ch][1]*d[ch][1] + d[ch][2]*d[ch][2]);
            const float s = 1.0f / fmaxf(nn, 1e-8f);
            dnS[t][ch * 3 + 0] = d[ch][0] * s;
            dnS[t][ch * 3 + 1] = d[ch][1] * s;
            dnS[t][ch * 3 + 2] = d[ch][2] * s;
        }
    }
    __syncthreads();

    const ushort* nA0 = nfsb + (size_t)rowi[lr]      * SDIM + lk * 8;
    const ushort* nA1 = nfsb + (size_t)rowi[lr + 16] * SDIM + lk * 8;
    const ushort* vA0 = vnb  + (size_t)coli[lr]      * HDIM + lk * 8;
    const ushort* vA1 = vnb  + (size_t)coli[lr + 16] * HDIM + lk * 8;

#define CM1_A(KS, A0, A1)                                                      \
    if ((KS) < 4)       { A0 = *(const bf16x8*)(nA0 + (KS) * 32);              \
                          A1 = *(const bf16x8*)(nA1 + (KS) * 32); }            \
    else if ((KS) < 12) { A0 = *(const bf16x8*)(vA0 + (KS) * 32 - 128);        \
                          A1 = *(const bf16x8*)(vA1 + (KS) * 32 - 128); }      \
    else if (lk < 2)    { A0 = *(const bf16x8*)&ipB[lr * 16 + lk * 8];         \
                          A1 = *(const bf16x8*)&ipB[(lr + 16) * 16 + lk * 8]; }\
    else                { A0 = (bf16x8)(short)0; A1 = (bf16x8)(short)0; }

    f32x4 acc[2][4];

    // ===== cm layer 1 (K=416), prefetched =====
    {
        #pragma unroll
        for (int mt = 0; mt < 2; ++mt)
            #pragma unroll
            for (int nt = 0; nt < 4; ++nt) acc[mt][nt] = (f32x4)0.f;
        bf16x8 a0c, a1c;
        CM1_A(0, a0c, a1c);
        bf16x8 b0c = *(const bf16x8*)&w1t[(size_t)(colBase + lr) * 416 + lk * 8];
        bf16x8 b1c = *(const bf16x8*)&w1t[(size_t)(colBase + 16 + lr) * 416 + lk * 8];
        bf16x8 b2c = *(const bf16x8*)&w1t[(size_t)(colBase + 32 + lr) * 416 + lk * 8];
        bf16x8 b3c = *(const bf16x8*)&w1t[(size_t)(colBase + 48 + lr) * 416 + lk * 8];
        #pragma unroll
        for (int ks = 0; ks < 13; ++ks) {
            bf16x8 a0n, a1n, b0n, b1n, b2n, b3n;
            if (ks < 12) {
                const int k1 = (ks + 1) * 32 + lk * 8;
                CM1_A(ks + 1, a0n, a1n);
                b0n = *(const bf16x8*)&w1t[(size_t)(colBase + lr) * 416 + k1];
                b1n = *(const bf16x8*)&w1t[(size_t)(colBase + 16 + lr) * 416 + k1];
                b2n = *(const bf16x8*)&w1t[(size_t)(colBase + 32 + lr) * 416 + k1];
                b3n = *(const bf16x8*)&w1t[(size_t)(colBase + 48 + lr) * 416 + k1];
            }
            acc[0][0] = __builtin_amdgcn_mfma_f32_16x16x32_bf16(a0c, b0c, acc[0][0], 0, 0, 0);
            acc[1][0] = __builtin_amdgcn_mfma_f32_16x16x32_bf16(a1c, b0c, acc[1][0], 0, 0, 0);
            acc[0][1] = __builtin_amdgcn_mfma_f32_16x16x32_bf16(a0c, b1c, acc[0][1], 0, 0, 0);
            acc[1][1] = __builtin_amdgcn_mfma_f32_16x16x32_bf16(a1c, b1c, acc[1][1], 0, 0, 0);
            acc[0][2] = __builtin_amdgcn_mfma_f32_16x16x32_bf16(a0c, b2c, acc[0][2], 0, 0, 0);
            acc[1][2] = __builtin_amdgcn_mfma_f32_16x16x32_bf16(a1c, b2c, acc[1][2], 0, 0, 0);
            acc[0][3] = __builtin_amdgcn_mfma_f32_16x16x32_bf16(a0c, b3c, acc[0][3], 0, 0, 0);
            acc[1][3] = __builtin_amdgcn_mfma_f32_16x16x32_bf16(a1c, b3c, acc[1][3], 0, 0, 0);
            if (ks < 12) { a0c = a0n; a1c = a1n; b0c = b0n; b1c = b1n; b2c = b2n; b3c = b3n; }
        }
    }
    EPI_SILU(Hd, b1);
    __syncthreads();

    // ===== cm layer 2 -> msg =====
    KLOOP_PF(Hd, w2t);
    #pragma unroll
    for (int nt = 0; nt < 4; ++nt) {
        const int col = colBase + nt * 16 + lr;
        const float bb = b2[col];
        #pragma unroll
        for (int mt = 0; mt < 2; ++mt)
            #pragma unroll
            for (int r = 0; r < 4; ++r) {
                const int row = mt * 16 + lk * 4 + r;
                Mg[row * MSTR + col] = f2b(acc[mt][nt][r] + bb);
            }
    }
    __syncthreads();

    // ===== segmented reduction msg -> agg_feat (thread t = column t) =====
    {
        float s = 0.f;
        int prev = rowi[0];
        for (int r = 0; r < 32; ++r) {
            const int rr = rowi[r];
            if (rr != prev) {
                atomicAdd(&agg_feat[(size_t)prev * HDIM + t], s);
                s = 0.f; prev = rr;
            }
            s += b2f(Mg[r * MSTR + t]);
        }
        atomicAdd(&agg_feat[(size_t)prev * HDIM + t], s);
    }

    // ===== vr layer 1 =====
    KLOOP_PF(Mg, vrw1t);
    EPI_SILU(Hd, vrb1);
    __syncthreads();

    // ===== vr layer 2 (wave 0) =====
    if (wv == 0) {
        f32x4 a2[2]; a2[0] = (f32x4)0.f; a2[1] = (f32x4)0.f;
        #pragma unroll
        for (int ks = 0; ks < 8; ++ks) {
            const bf16x8 a0 = *(const bf16x8*)&Hd[lr * MSTR + ks * 32 + lk * 8];
            const bf16x8 a1 = *(const bf16x8*)&Hd[(lr + 16) * MSTR + ks * 32 + lk * 8];
            const bf16x8 b  = *(const bf16x8*)&vrw2t[(size_t)lr * 256 + ks * 32 + lk * 8];
            a2[0] = __builtin_amdgcn_mfma_f32_16x16x32_bf16(a0, b, a2[0], 0, 0, 0);
            a2[1] = __builtin_amdgcn_mfma_f32_16x16x32_bf16(a1, b, a2[1], 0, 0, 0);
        }
        if (lr < 4) {
            const float bb = vrb2[lr];
            #pragma unroll
            for (int mt = 0; mt < 2; ++mt)
                #pragma unroll
                for (int r = 0; r < 4; ++r)
                    wvrS[mt * 16 + lk * 4 + r][lr] = a2[mt][r] + bb;
        }
    }
    __syncthreads();

    // ===== rv layer 1 =====
    KLOOP_PF(Mg, rvw1t);
    EPI_SILU(Hd, rvb1);
    __syncthreads();

    // ===== rv layer 2 (wave 0) =====
    if (wv == 0) {
        f32x4 a2[2]; a2[0] = (f32x4)0.f; a2[1] = (f32x4)0.f;
        #pragma unroll
        for (int ks = 0; ks < 8; ++ks) {
            const bf16x8 a0 = *(const bf16x8*)&Hd[lr * MSTR + ks * 32 + lk * 8];
            const bf16x8 a1 = *(const bf16x8*)&Hd[(lr + 16) * MSTR + ks * 32 + lk * 8];
            const bf16x8 b  = *(const bf16x8*)&rvw2t[(size_t)lr * 256 + ks * 32 + lk * 8];
            a2[0] = __builtin_amdgcn_mfma_f32_16x16x32_bf16(a0, b, a2[0], 0, 0, 0);
            a2[1] = __builtin_amdgcn_mfma_f32_16x16x32_bf16(a1, b, a2[1], 0, 0, 0);
        }
        const float bb = rvb2[lr];
        #pragma unroll
        for (int mt = 0; mt < 2; ++mt)
            #pragma unroll
            for (int r = 0; r < 4; ++r)
                wrvS[mt * 16 + lk * 4 + r][lr] = a2[mt][r] + bb;
    }
    __syncthreads();

    // ===== per-edge geometric update (t<32) =====
    if (t < 32) {
        float wvv[4], wrr[16], dn[12], ev[15];
        #pragma unroll
        for (int c = 0; c < 4; ++c)  wvv[c] = wvrS[t][c];
        #pragma unroll
        for (int i = 0; i < 16; ++i) wrr[i] = wrvS[t][i];
        #pragma unroll
        for (int i = 0; i < 12; ++i) dn[i]  = dnS[t][i];
        #pragma unroll
        for (int j = 0; j < 3; ++j) {
            float v = 0.f;
            #pragma unroll
            for (int c = 0; c < 4; ++c) v = fmaf(wvv[c], dn[c * 3 + j], v);
            ev[j] = 0.5f * v;
        }
        #pragma unroll
        for (int u = 0; u < 4; ++u)
            #pragma unroll
            for (int j = 0; j < 3; ++j) {
                float v = 0.f;
                #pragma unroll
                for (int c = 0; c < 4; ++c) v = fmaf(wrr[c * 4 + u], dn[c * 3 + j], v);
                ev[3 + u * 3 + j] = -0.5f * v;
            }
        #pragma unroll
        for (int i = 0; i < 15; ++i) wrvS[t][i] = ev[i];
    }
    __syncthreads();

    // ===== segmented reduction vr/rv (t<15) =====
    if (t < 15) {
        float s = 0.f;
        int prev = rowi[0];
        for (int r = 0; r < 32; ++r) {
            const int rr = rowi[r];
            if (rr != prev) {
                if (t < 3) atomicAdd(&agg_vr[(size_t)prev * 3 + t], s);
                else       atomicAdd(&agg_rv[(size_t)prev * 12 + (t - 3)], s);
                s = 0.f; prev = rr;
            }
            s += wrvS[r][t];
        }
        if (t < 3) atomicAdd(&agg_vr[(size_t)prev * 3 + t], s);
        else       atomicAdd(&agg_rv[(size_t)prev * 12 + (t - 3)], s);
    }
#undef CM1_A
}

// ---------------------------------------------------------------- k_node (MFMA)
// 32 nodes/block (20000 = 625*32 exact), 256 threads = 4 waves.
__global__ __launch_bounds__(256, 4) void k_node(
    const float* __restrict__ node_feat, const float* __restrict__ node_pos,
    const float* __restrict__ vn_feat, const float* __restrict__ vn_pos,
    const float* __restrict__ agg_feat, const float* __restrict__ agg_vr,
    const float* __restrict__ agg_rv, const float* __restrict__ cntf,
    const ushort* __restrict__ wb,
    const float* __restrict__ ftb1, const float* __restrict__ ftb2,
    const float* __restrict__ f2tb1, const float* __restrict__ f2tb2,
    const float* __restrict__ vfb1, const float* __restrict__ vfb2,
    float* __restrict__ out, int Nn)
{
    __shared__ ushort Ab[32 * MSTR];
    __shared__ ushort Hd[32 * MSTR];
    __shared__ float rc[32];
    const int t  = threadIdx.x;
    const int n0 = blockIdx.x * 32;
    const int wv = t >> 6;
    const int lane = t & 63;
    const int lr = lane & 15;
    const int lk = lane >> 4;
    const int colBase = wv * 64;

    float* nf_out = out;
    float* np_out = out + (size_t)Nn * FEAT;
    float* vf_out = np_out + (size_t)Nn * 3;
    float* vp_out = vf_out + (size_t)Nn * HDIM;

    if (t < 32) rc[t] = 1.0f / fmaxf(cntf[n0 + t], 1.0f);
    __syncthreads();
    // Ab = bf16(agg_feat / cnt)
    #pragma unroll
    for (int i = 0; i < 8; ++i) {
        const int p = t + i * 256;
        const int r = p >> 6, cc = (p & 63) * 4;
        float4 v = *(const float4*)&agg_feat[(size_t)(n0 + r) * HDIM + cc];
        const float s = rc[r];
        ushort4 o;
        o.x = f2b(v.x * s); o.y = f2b(v.y * s);
        o.z = f2b(v.z * s); o.w = f2b(v.w * s);
        *(ushort4*)&Ab[r * MSTR + cc] = o;
    }
    __syncthreads();

    f32x4 acc[2][4];

    // ---- vf MLP ----
    KLOOP_PF(Ab, wb + OVF1);
    EPI_SILU(Hd, vfb1);
    __syncthreads();
    KLOOP_PF(Hd, wb + OVF2);
    #pragma unroll
    for (int nt = 0; nt < 4; ++nt) {
        const int col = colBase + nt * 16 + lr;
        const float bb = vfb2[col];
        #pragma unroll
        for (int mt = 0; mt < 2; ++mt)
            #pragma unroll
            for (int r = 0; r < 4; ++r) {
                const int row = mt * 16 + lk * 4 + r;
                const size_t o = (size_t)(n0 + row) * HDIM + col;
                vf_out[o] = vn_feat[o] + acc[mt][nt][r] + bb;
            }
    }
    __syncthreads();

    // ---- ft MLP ----
    KLOOP_PF(Ab, wb + OFT1);
    EPI_SILU(Hd, ftb1);
    __syncthreads();
    KLOOP_PF(Hd, wb + OFT2);
    #pragma unroll
    for (int nt = 0; nt < 4; ++nt) {               // x2 -> Ab (bf16)
        const int col = colBase + nt * 16 + lr;
        const float bb = ftb2[col];
        #pragma unroll
        for (int mt = 0; mt < 2; ++mt)
            #pragma unroll
            for (int r = 0; r < 4; ++r) {
                const int row = mt * 16 + lk * 4 + r;
                Ab[row * MSTR + col] = f2b(acc[mt][nt][r] + bb);
            }
    }
    __syncthreads();

    // ---- f2t MLP ----
    KLOOP_PF(Ab, wb + OF2T1);
    EPI_SILU(Hd, f2tb1);
    __syncthreads();
    {   // layer 2, N=128: 4 waves x 32 cols
        const ushort* w2p = wb + OF2T2;
        const int colB2 = wv * 32;
        f32x4 a2[2][2];
        #pragma unroll
        for (int mt = 0; mt < 2; ++mt)
            #pragma unroll
            for (int nt = 0; nt < 2; ++nt) a2[mt][nt] = (f32x4)0.f;
        #pragma unroll
        for (int ks = 0; ks < 8; ++ks) {
            const int k0 = ks * 32 + lk * 8;
            const bf16x8 a0 = *(const bf16x8*)&Hd[lr * MSTR + k0];
            const bf16x8 a1 = *(const bf16x8*)&Hd[(lr + 16) * MSTR + k0];
            const bf16x8 w0 = *(const bf16x8*)&w2p[(size_t)(colB2 + lr) * 256 + k0];
            const bf16x8 w1v = *(const bf16x8*)&w2p[(size_t)(colB2 + 16 + lr) * 256 + k0];
            a2[0][0] = __builtin_amdgcn_mfma_f32_16x16x32_bf16(a0, w0, a2[0][0], 0, 0, 0);
            a2[1][0] = __builtin_amdgcn_mfma_f32_16x16x32_bf16(a1, w0, a2[1][0], 0, 0, 0);
            a2[0][1] = __builtin_amdgcn_mfma_f32_16x16x32_bf16(a0, w1v, a2[0][1], 0, 0, 0);
            a2[1][1] = __builtin_amdgcn_mfma_f32_16x16x32_bf16(a1, w1v, a2[1][1], 0, 0, 0);
        }
        #pragma unroll
        for (int nt = 0; nt < 2; ++nt) {
            const int col = colB2 + nt * 16 + lr;
            const float bb = f2tb2[col];
            #pragma unroll
            for (int mt = 0; mt < 2; ++mt)
                #pragma unroll
                for (int r = 0; r < 4; ++r) {
                    const int row = mt * 16 + lk * 4 + r;
                    const size_t o = (size_t)(n0 + row) * FEAT + col;
                    nf_out[o] = node_feat[o] + a2[mt][nt][r] + bb;
                }
        }
    }

    // passthrough cols 128..479 (88 float4 per row)
    for (int p = t; p < 32 * 88; p += 256) {
        const int r = p / 88;
        const int cc = 128 + (p % 88) * 4;
        const size_t o = (size_t)(n0 + r) * FEAT + cc;
        *(float4*)&nf_out[o] = *(const float4*)&node_feat[o];
    }
    // position outputs
    if (t < 32) {
        const int n = n0 + t;
        const float s = rc[t];
        #pragma unroll
        for (int j = 0; j < 3; ++j)
            np_out[(size_t)n * 3 + j] = node_pos[(size_t)n * 3 + j] + agg_vr[(size_t)n * 3 + j] * s;
        #pragma unroll
        for (int j = 0; j < 12; ++j)
            vp_out[(size_t)n * 12 + j] = vn_pos[(size_t)n * 12 + j] + agg_rv[(size_t)n * 12 + j] * s;
    }
}

// ---------------------------------------------------------------- launch
extern "C" void kernel_launch(void* const* d_in, const int* in_sizes, int n_in,
                              void* d_out, int out_size, void* d_ws, size_t ws_size,
                              hipStream_t stream)
{
    (void)n_in; (void)out_size; (void)ws_size;
    const float* node_feat = (const float*)d_in[0];
    const float* node_pos  = (const float*)d_in[1];
    const float* vn_feat   = (const float*)d_in[2];
    const float* vn_pos    = (const float*)d_in[3];
    const int*   eidx      = (const int*)d_in[4];
    const float* w_scalar  = (const float*)d_in[5];
    const float* cm_w1  = (const float*)d_in[6];
    const float* cm_b1  = (const float*)d_in[7];
    const float* cm_w2  = (const float*)d_in[8];
    const float* cm_b2  = (const float*)d_in[9];
    const float* vr_w1  = (const float*)d_in[10];
    const float* vr_b1  = (const float*)d_in[11];
    const float* vr_w2  = (const float*)d_in[12];
    const float* vr_b2  = (const float*)d_in[13];
    const float* rv_w1  = (const float*)d_in[14];
    const float* rv_b1  = (const float*)d_in[15];
    const float* rv_w2  = (const float*)d_in[16];
    const float* rv_b2  = (const float*)d_in[17];
    const float* ft_w1  = (const float*)d_in[18];
    const float* ft_b1  = (const float*)d_in[19];
    const float* ft_w2  = (const float*)d_in[20];
    const float* ft_b2  = (const float*)d_in[21];
    const float* f2t_w1 = (const float*)d_in[22];
    const float* f2t_b1 = (const float*)d_in[23];
    const float* f2t_w2 = (const float*)d_in[24];
    const float* f2t_b2 = (const float*)d_in[25];
    const float* vf_w1  = (const float*)d_in[26];
    const float* vf_b1  = (const float*)d_in[27];
    const float* vf_w2  = (const float*)d_in[28];
    const float* vf_b2  = (const float*)d_in[29];

    const int Nn = in_sizes[0] / FEAT;        // 20000
    const int E  = in_sizes[4] / 2;           // 240000

    // workspace layout
    float* ws       = (float*)d_ws;
    float* agg_feat = ws;                                // Nn*256 (zeroed)
    float* agg_vr   = agg_feat + (size_t)Nn * HDIM;      // Nn*3   (zeroed)
    float* agg_rv   = agg_vr   + (size_t)Nn * 3;         // Nn*12  (zeroed)
    float* cntf     = agg_rv   + (size_t)Nn * 12;        // Nn     (zeroed)
    int*   cnt_i    = (int*)(cntf + Nn);                 // Nn     (zeroed)
    int*   cursor   = cnt_i + Nn;                        // Nn     (zeroed)
    int*   rowstart = cursor + Nn;                       // Nn+16
    int*   elist    = rowstart + Nn + 16;                // E
    ushort* nfsb = (ushort*)(elist + E);                 // Nn*128
    ushort* vnb  = nfsb + (size_t)Nn * SDIM;             // Nn*256
    ushort* wb   = vnb  + (size_t)Nn * HDIM;             // OWTOT

    const size_t zero_bytes = (size_t)Nn * (HDIM + 3 + 12 + 1 + 2) * sizeof(float);
    hipMemsetAsync(agg_feat, 0, zero_bytes, stream);

    const int eg = (E + 255) / 256;
    k_count<<<eg, 256, 0, stream>>>(eidx, cnt_i, E);
    k_scan<<<1, 1024, 0, stream>>>(cnt_i, rowstart, cntf, Nn);
    k_place<<<eg, 256, 0, stream>>>(eidx, rowstart, cursor, elist, E);
    k_wprep<<<(OWTOT + 255) / 256, 256, 0, stream>>>(
        cm_w1, cm_w2, vr_w1, rv_w1, vr_w2, rv_w2,
        ft_w1, ft_w2, f2t_w1, f2t_w2, vf_w1, vf_w2, wb);
    k_vnb<<<(Nn * 64 + 255) / 256, 256, 0, stream>>>(vn_feat, vnb, Nn * 64);
    k_nfs<<<Nn / 32, 256, 0, stream>>>(node_feat, w_scalar, nfsb);
    k_edge<<<E / 32, 256, 0, stream>>>(nfsb, vnb, node_pos, vn_pos, eidx, elist,
                                       wb, cm_b1, cm_b2, vr_b1, vr_b2, rv_b1, rv_b2,
                                       agg_feat, agg_vr, agg_rv, E);
    k_node<<<Nn / 32, 256, 0, stream>>>(node_feat, node_pos, vn_feat, vn_pos,
                                        agg_feat, agg_vr, agg_rv, cntf, wb,
                                        ft_b1, ft_b2, f2t_b1, f2t_b2, vf_b1, vf_b2,
                                        (float*)d_out, Nn);
}